// Round 9
// baseline (92.955 us; speedup 1.0000x reference)
//
#include <hip/hip_runtime.h>
#include <math.h>

#define T_SEQ 2048
#define NH    16
#define NKV   4
// ws layout: tb (sin/cos table, 512KB) @0 ; Kr f16 @1MB (2MB) ; Vt f16 @3MB (2MB) ;
//            Wt f16 @5MB (2MB) ; AO f16 @7MB (8MB). Total 15MB.

typedef __attribute__((ext_vector_type(8)))  _Float16 f16x8;
typedef __attribute__((ext_vector_type(4)))  _Float16 f16x4;
typedef __attribute__((ext_vector_type(2)))  __fp16   fp16x2b;  // cvt_pkrtz result type
typedef __attribute__((ext_vector_type(4)))  float    f32x4;
typedef __attribute__((ext_vector_type(16))) float    f32x16;

#if __has_builtin(__builtin_amdgcn_exp2f)
#define EXP2F(x) __builtin_amdgcn_exp2f(x)
#else
#define EXP2F(x) exp2f(x)
#endif

// 0.125 (1/sqrt(64)) * log2(e): QK^T scores land directly in log2 domain.
#define QSCALE 0.18033688011112042f

// LDS-producer barrier that does NOT drain vmcnt: global prefetch loads stay
// in flight across tiles (T4). lgkmcnt(0) makes this wave's ds_writes/reads
// visible/complete; sched_barrier(0) pins ordering (rule #18).
#define LDS_BARRIER()                                        \
    do {                                                     \
        __builtin_amdgcn_sched_barrier(0);                   \
        asm volatile("s_waitcnt lgkmcnt(0)" ::: "memory");   \
        __builtin_amdgcn_s_barrier();                        \
        __builtin_amdgcn_sched_barrier(0);                   \
    } while (0)

// ---------------- fused prep: table | rope_k | V-transpose | W-transpose ------
__global__ __launch_bounds__(256) void prep_kernel(const float* __restrict__ k,
                                                   const float* __restrict__ v,
                                                   const float* __restrict__ w,
                                                   float2* __restrict__ tb,
                                                   _Float16* __restrict__ Kr,
                                                   _Float16* __restrict__ Vt,
                                                   _Float16* __restrict__ Wt)
{
    __shared__ _Float16 L[64 * 72];
    const int bx = blockIdx.x;
    if (bx < 256) {
        // sin/cos table: tb[t*32+i] = {cos, sin}(t * 10000^(-i/32))
        int idx = bx * 256 + threadIdx.x;
        int i = idx & 31, t = idx >> 5;
        float inv = __expf((float)i * (-9.210340371976184f / 32.0f));
        float ang = (float)t * inv;
        tb[idx] = make_float2(cosf(ang), sinf(ang));
    } else if (bx < 2304) {
        // K RoPE (inline trig; independent of tb)
        int idx = (bx - 256) * 256 + threadIdx.x;     // [0, 2*4*2048*32)
        int i   = idx & 31;
        int t   = (idx >> 5) & 2047;
        int bk  = idx >> 16;                          // b*4+kh
        float inv = __expf((float)i * (-9.210340371976184f / 32.0f));
        float ang = (float)t * inv;
        float sn = sinf(ang), cs = cosf(ang);
        const float* src = k + ((size_t)(bk >> 2) * T_SEQ + t) * 256 + (bk & 3) * 64 + i;
        float x1 = src[0], x2 = src[32];
        _Float16* dst = Kr + ((size_t)bk * T_SEQ + t) * 64 + i;
        dst[0]  = (_Float16)(x1 * cs - x2 * sn);
        dst[32] = (_Float16)(x2 * cs + x1 * sn);
    } else if (bx < 2560) {
        // V transpose via LDS (both sides coalesced)
        const int id = bx - 2304;                     // 32 t-tiles x 8 bk
        const int t0 = (id & 31) * 64, bk = id >> 5;
        const int b = bk >> 2, kh = bk & 3;
        const int rr = threadIdx.x >> 2, pp = threadIdx.x & 3;
        const float* src = v + ((size_t)(b * T_SEQ + t0 + rr)) * 256 + kh * 64 + pp * 16;
        f32x4 s0 = *(const f32x4*)(src), s1 = *(const f32x4*)(src + 4);
        f32x4 s2 = *(const f32x4*)(src + 8), s3 = *(const f32x4*)(src + 12);
        _Float16* lp = &L[rr * 72 + pp * 16];
        #pragma unroll
        for (int j = 0; j < 4; ++j) { lp[j] = (_Float16)s0[j]; lp[4+j] = (_Float16)s1[j];
                                      lp[8+j] = (_Float16)s2[j]; lp[12+j] = (_Float16)s3[j]; }
        __syncthreads();
        f16x8 w0, w1;
        #pragma unroll
        for (int j = 0; j < 8; ++j) w0[j] = L[(pp * 16 + j) * 72 + rr];
        #pragma unroll
        for (int j = 0; j < 8; ++j) w1[j] = L[(pp * 16 + 8 + j) * 72 + rr];
        _Float16* dst = Vt + ((size_t)bk * 64 + rr) * T_SEQ + t0 + pp * 16;
        *(f16x8*)dst = w0; *(f16x8*)(dst + 8) = w1;
    } else {
        // W transpose via LDS
        const int id = bx - 2560;                     // 16 k-tiles x 16 n-tiles
        const int k0 = (id & 15) * 64, n0 = (id >> 4) * 64;
        const int rr = threadIdx.x >> 2, pp = threadIdx.x & 3;
        const float* src = w + (size_t)(k0 + rr) * 1024 + n0 + pp * 16;
        f32x4 s0 = *(const f32x4*)(src), s1 = *(const f32x4*)(src + 4);
        f32x4 s2 = *(const f32x4*)(src + 8), s3 = *(const f32x4*)(src + 12);
        _Float16* lp = &L[rr * 72 + pp * 16];
        #pragma unroll
        for (int j = 0; j < 4; ++j) { lp[j] = (_Float16)s0[j]; lp[4+j] = (_Float16)s1[j];
                                      lp[8+j] = (_Float16)s2[j]; lp[12+j] = (_Float16)s3[j]; }
        __syncthreads();
        f16x8 w0, w1;
        #pragma unroll
        for (int j = 0; j < 8; ++j) w0[j] = L[(pp * 16 + j) * 72 + rr];
        #pragma unroll
        for (int j = 0; j < 8; ++j) w1[j] = L[(pp * 16 + 8 + j) * 72 + rr];
        _Float16* dst = Wt + (size_t)(n0 + rr) * 1024 + k0 + pp * 16;
        *(f16x8*)dst = w0; *(f16x8*)(dst + 8) = w1;
    }
}

// ---------------- flash attention: intra-block causal pairing, 32x32 MFMA ----
// Block = 4 waves handles chunk pair (p, 31-p) of 64 q-rows each: waves 0,1 ->
// chunk p, waves 2,3 -> chunk 31-p. One shared KV stream of 32-p tiles; MFMA
// work = exactly 33 tile-units per block (uniform) -> all blocks take equal
// time -> both CU-resident blocks (bids i, i+256 share a CU; 256 % 16 == 0 so
// same p) live for the whole wall. Raw lgkm-only barrier keeps depth-2 global
// prefetch in flight across tiles (no vmcnt(0) in the loop).

__global__ __launch_bounds__(256) void attn_kernel(const float* __restrict__ q,
                                                   const float2* __restrict__ tb,
                                                   const _Float16* __restrict__ Kr,
                                                   const _Float16* __restrict__ Vt,
                                                   _Float16* __restrict__ AO)
{
    __shared__ _Float16 smem[16384];   // Ks[2]@0/4096, Vs[2]@8192/12288; Os reuse

    const int tid  = threadIdx.x;
    const int wid  = tid >> 6;
    const int lane = tid & 63;
    const int bid = blockIdx.x;
    const int p   = bid & 15;                      // pair id: chunks (p, 31-p)
    const int bh  = bid >> 4;                      // 0..31 = b*16+h
    const int b = bh >> 4, h = bh & 15;
    const int bkh = b * NKV + (h >> 2);
    const int hi = lane >> 5;                      // half-wave
    const int qc = lane & 31;                      // q within band / A-row index
    const int chunk = (wid < 2) ? p : (31 - p);    // this wave's 64-row chunk
    const int qlo = chunk * 64 + (wid & 1) * 32;   // wave's 32-row band start
    const int tq  = qlo + qc;                      // this lane's stat-q row
    const int NT  = 32 - p;                        // shared KV stream length

    // ---- staging geometry (256 threads stage 64x64 K + 64x64 V per tile) ----
    const int srow   = wid * 16 + (lane >> 3);
    const int schunk = lane & 7;
    const _Float16* kgbase = Kr + (size_t)bkh * T_SEQ * 64;
    const _Float16* vgbase = Vt + (size_t)bkh * 64 * T_SEQ;
    const int kd0 = srow * 64 + ((schunk ^ (srow & 7)) * 8);
    const int kd1 = kd0 + 8 * 64;

    // two named staging register sets (ping-pong; rule #20: no dynamic index)
    f16x8 sAK0, sAK1, sAV0, sAV1, sBK0, sBK1, sBV0, sBV1;
    {   // prologue: issue T0 loads first
        const _Float16* kg = kgbase + (size_t)srow * 64 + schunk * 8;
        sAK0 = *(const f16x8*)(kg);
        sAK1 = *(const f16x8*)(kg + 8 * 64);
        const _Float16* vg = vgbase + (size_t)srow * T_SEQ + schunk * 8;
        sAV0 = *(const f16x8*)(vg);
        sAV1 = *(const f16x8*)(vg + 8 * T_SEQ);
    }

    // ---- Q load + RoPE into B-frags qa[ds] (hides T0 latency) ----
    f16x8 qa[4];
    {
        const float* qrow = q + ((size_t)b * T_SEQ + tq) * 1024 + h * 64;
        float raw[4][8];
        #pragma unroll
        for (int ds = 0; ds < 4; ++ds) {
            f32x4 r0 = *(const f32x4*)(qrow + 16 * ds + 8 * hi);
            f32x4 r1 = *(const f32x4*)(qrow + 16 * ds + 8 * hi + 4);
            #pragma unroll
            for (int j = 0; j < 4; ++j) { raw[ds][j] = r0[j]; raw[ds][4 + j] = r1[j]; }
        }
        #pragma unroll
        for (int ds = 0; ds < 2; ++ds) {
            const float2* tp = tb + (size_t)tq * 32 + 16 * ds + 8 * hi;
            #pragma unroll
            for (int j = 0; j < 8; ++j) {
                float2 cs = tp[j];
                float x0 = raw[ds][j], x1 = raw[ds + 2][j];
                qa[ds][j]     = (_Float16)((x0 * cs.x - x1 * cs.y) * QSCALE);
                qa[ds + 2][j] = (_Float16)((x1 * cs.x + x0 * cs.y) * QSCALE);
            }
        }
    }

    // write T0 -> buf0, then issue T1 into setB
    *(f16x8*)(&smem[kd0])        = sAK0;
    *(f16x8*)(&smem[kd1])        = sAK1;
    *(f16x8*)(&smem[8192 + kd0]) = sAV0;
    *(f16x8*)(&smem[8192 + kd1]) = sAV1;
    if (NT > 1) {
        const _Float16* kg = kgbase + (size_t)(64 + srow) * 64 + schunk * 8;
        sBK0 = *(const f16x8*)(kg);
        sBK1 = *(const f16x8*)(kg + 8 * 64);
        const _Float16* vg = vgbase + (size_t)srow * T_SEQ + 64 + schunk * 8;
        sBV0 = *(const f16x8*)(vg);
        sBV1 = *(const f16x8*)(vg + 8 * T_SEQ);
    }
    LDS_BARRIER();

    f32x16 o0, o1;                                 // O[q=crow(r,hi)][d = db*32+qc]
    #pragma unroll
    for (int i = 0; i < 16; ++i) { o0[i] = 0.f; o1[i] = 0.f; }
    float mrun = -INFINITY, lsum = 0.0f;

    // tile body: issue T(t+2) into set I, compute buf[t&1], write set O (T(t+1))
    auto tile_body = [&](int kvb,
                         f16x8& iK0, f16x8& iK1, f16x8& iV0, f16x8& iV1,
                         f16x8& oK0, f16x8& oK1, f16x8& oV0, f16x8& oV1) {
        if (kvb + 2 < NT) {
            const int nb = (kvb + 2) * 64;
            const _Float16* kg = kgbase + (size_t)(nb + srow) * 64 + schunk * 8;
            iK0 = *(const f16x8*)(kg);
            iK1 = *(const f16x8*)(kg + 8 * 64);
            const _Float16* vg = vgbase + (size_t)srow * T_SEQ + nb + schunk * 8;
            iV0 = *(const f16x8*)(vg);
            iV1 = *(const f16x8*)(vg + 8 * T_SEQ);
        }
        const _Float16* ks = smem + (kvb & 1) * 4096;
        const _Float16* vs = smem + 8192 + (kvb & 1) * 4096;

        const int rel = kvb * 64 - qlo;
        if (rel <= 0) {
            const bool act1 = (rel <= -32);
            // ---- QK^T: S^T[key 32][q 32], s0/s1 chains interleaved ----
            f32x16 s0, s1;
            #pragma unroll
            for (int i = 0; i < 16; ++i) { s0[i] = 0.f; s1[i] = 0.f; }
            __builtin_amdgcn_s_setprio(1);
            {
                const int r0 = qc, rsw0 = qc & 7;
                const int r1 = 32 + qc;            // (32+qc)&7 == qc&7
                #pragma unroll
                for (int ds = 0; ds < 4; ++ds) {
                    f16x8 ka0 = *(const f16x8*)(ks + r0 * 64 + (((2*ds + hi) ^ rsw0) * 8));
                    s0 = __builtin_amdgcn_mfma_f32_32x32x16_f16(ka0, qa[ds], s0, 0, 0, 0);
                    if (act1) {
                        f16x8 ka1 = *(const f16x8*)(ks + r1 * 64 + (((2*ds + hi) ^ rsw0) * 8));
                        s1 = __builtin_amdgcn_mfma_f32_32x32x16_f16(ka1, qa[ds], s1, 0, 0, 0);
                    }
                }
            }
            __builtin_amdgcn_s_setprio(0);

            // ---- diagonal masking ----
            if (rel == 0) {
                #pragma unroll
                for (int r = 0; r < 16; ++r)
                    if ((r & 3) + 8 * (r >> 2) + 4 * hi > qc) s0[r] = -1e30f;
            }
            if (act1 && rel == -32) {
                #pragma unroll
                for (int r = 0; r < 16; ++r)
                    if ((r & 3) + 8 * (r >> 2) + 4 * hi > qc) s1[r] = -1e30f;
            }

            // ---- online softmax (log2 domain, defer-rescale THR=8) ----
            float mt[8];
            #pragma unroll
            for (int i = 0; i < 8; ++i) mt[i] = fmaxf(s0[2*i], s0[2*i+1]);
            if (act1) {
                #pragma unroll
                for (int i = 0; i < 8; ++i)
                    mt[i] = fmaxf(mt[i], fmaxf(s1[2*i], s1[2*i+1]));
            }
            #pragma unroll
            for (int i = 0; i < 4; ++i) mt[i] = fmaxf(mt[i], mt[i+4]);
            float pmL = fmaxf(fmaxf(mt[0], mt[1]), fmaxf(mt[2], mt[3]));
            if (!__all(pmL <= mrun + 8.0f)) {
                float pm = fmaxf(pmL, __shfl_xor(pmL, 32));
                float mn = fmaxf(mrun, pm);
                float corr = EXP2F(mrun - mn);
                mrun = mn;
                lsum *= corr;
                #pragma unroll
                for (int r = 0; r < 16; ++r) {
                    float cfr = __shfl(corr, (r & 3) + 8 * (r >> 2) + 4 * hi);
                    o0[r] *= cfr; o1[r] *= cfr;
                }
            }

            // ---- exp2 + pack P; row-sum via 2 partial chains ----
            unsigned pk0[8], pk1[8];
            float psa = 0.0f, psb = 0.0f;
            #pragma unroll
            for (int i = 0; i < 8; ++i) {
                float p0 = EXP2F(s0[2*i]     - mrun);
                float p1 = EXP2F(s0[2*i + 1] - mrun);
                psa += p0; psb += p1;
                union { fp16x2b hh; unsigned u; } cv;
                cv.hh = __builtin_amdgcn_cvt_pkrtz(p0, p1);
                pk0[i] = cv.u;
            }
            if (act1) {
                #pragma unroll
                for (int i = 0; i < 8; ++i) {
                    float p0 = EXP2F(s1[2*i]     - mrun);
                    float p1 = EXP2F(s1[2*i + 1] - mrun);
                    psa += p0; psb += p1;
                    union { fp16x2b hh; unsigned u; } cv;
                    cv.hh = __builtin_amdgcn_cvt_pkrtz(p0, p1);
                    pk1[i] = cv.u;
                }
            }
            lsum += psa + psb;

            // ---- P repack to PV A-frags ----
            union { unsigned u[4]; f16x8 v; } af[4];
            {
                unsigned t0 = (unsigned)__shfl_xor((int)(hi ? pk0[0] : pk0[2]), 32);
                unsigned t1 = (unsigned)__shfl_xor((int)(hi ? pk0[1] : pk0[3]), 32);
                unsigned t2 = (unsigned)__shfl_xor((int)(hi ? pk0[4] : pk0[6]), 32);
                unsigned t3 = (unsigned)__shfl_xor((int)(hi ? pk0[5] : pk0[7]), 32);
                af[0].u[0] = hi ? t0 : pk0[0]; af[0].u[1] = hi ? t1 : pk0[1];
                af[0].u[2] = hi ? pk0[2] : t0; af[0].u[3] = hi ? pk0[3] : t1;
                af[1].u[0] = hi ? t2 : pk0[4]; af[1].u[1] = hi ? t3 : pk0[5];
                af[1].u[2] = hi ? pk0[6] : t2; af[1].u[3] = hi ? pk0[7] : t3;
            }
            if (act1) {
                unsigned t0 = (unsigned)__shfl_xor((int)(hi ? pk1[0] : pk1[2]), 32);
                unsigned t1 = (unsigned)__shfl_xor((int)(hi ? pk1[1] : pk1[3]), 32);
                unsigned t2 = (unsigned)__shfl_xor((int)(hi ? pk1[4] : pk1[6]), 32);
                unsigned t3 = (unsigned)__shfl_xor((int)(hi ? pk1[5] : pk1[7]), 32);
                af[2].u[0] = hi ? t0 : pk1[0]; af[2].u[1] = hi ? t1 : pk1[1];
                af[2].u[2] = hi ? pk1[2] : t0; af[2].u[3] = hi ? pk1[3] : t1;
                af[3].u[0] = hi ? t2 : pk1[4]; af[3].u[1] = hi ? t3 : pk1[5];
                af[3].u[2] = hi ? pk1[6] : t2; af[3].u[3] = hi ? pk1[7] : t3;
            }

            // ---- PV ----
            __builtin_amdgcn_s_setprio(1);
            const int nkc = act1 ? 4 : 2;
            #pragma unroll
            for (int kc = 0; kc < 4; ++kc) {
                if (kc < nkc) {
                    const int vr0 = qc;
                    const int vr1 = 32 + qc;
                    f16x8 vb0 = *(const f16x8*)(vs + vr0 * 64 + (((2*kc + hi) ^ (vr0 & 7)) * 8));
                    f16x8 vb1 = *(const f16x8*)(vs + vr1 * 64 + (((2*kc + hi) ^ (vr1 & 7)) * 8));
                    o0 = __builtin_amdgcn_mfma_f32_32x32x16_f16(af[kc].v, vb0, o0, 0, 0, 0);
                    o1 = __builtin_amdgcn_mfma_f32_32x32x16_f16(af[kc].v, vb1, o1, 0, 0, 0);
                }
            }
            __builtin_amdgcn_s_setprio(0);
        }

        // write T(kvb+1) (loaded a full tile ago -> complete, no vmcnt stall)
        if (kvb + 1 < NT) {
            _Float16* kw = smem + ((kvb + 1) & 1) * 4096;
            _Float16* vw = smem + 8192 + ((kvb + 1) & 1) * 4096;
            *(f16x8*)(&kw[kd0]) = oK0;
            *(f16x8*)(&kw[kd1]) = oK1;
            *(f16x8*)(&vw[kd0]) = oV0;
            *(f16x8*)(&vw[kd1]) = oV1;
        }
        LDS_BARRIER();   // drains LDS only; global prefetch stays in flight
    };

    for (int t = 0; t < NT; ) {
        tile_body(t, sAK0, sAK1, sAV0, sAV1, sBK0, sBK1, sBV0, sBV1); ++t;
        if (t >= NT) break;
        tile_body(t, sBK0, sBK1, sBV0, sBV1, sAK0, sAK1, sAV0, sAV1); ++t;
    }

    // ---- epilogue: normalize (lane-pair merged lsum), LDS bounce, store ----
    lsum += __shfl_xor(lsum, 32);
    const float li = 1.0f / lsum;
    __syncthreads();   // full drain before reusing smem as Os
    {
        _Float16* Os = smem;                       // [128][72]
        #pragma unroll
        for (int r = 0; r < 16; ++r) {
            const int crow = (r & 3) + 8 * (r >> 2) + 4 * hi;
            float lir = __shfl(li, crow);
            Os[(wid * 32 + crow) * 72 + qc]      = (_Float16)(o0[r] * lir);
            Os[(wid * 32 + crow) * 72 + 32 + qc] = (_Float16)(o1[r] * lir);
        }
    }
    __syncthreads();
    {
        const int row = tid >> 1, part = tid & 1;
        const int wsrc = row >> 5;                 // source wave of this row
        const int chs  = (wsrc < 2) ? p : (31 - p);
        const int grow = chs * 64 + (wsrc & 1) * 32 + (row & 31);
        const _Float16* src = smem + row * 72 + part * 32;
        _Float16* dst = AO + ((size_t)b * T_SEQ + grow) * 1024 + h * 64 + part * 32;
        #pragma unroll
        for (int j = 0; j < 4; ++j)
            *(f16x8*)(dst + j * 8) = *(const f16x8*)(src + j * 8);
    }
}

// ---------------- projection GEMM: out[4096][1024] = AO * Wt^T ----------------
// 128x64 tile (512 blocks -> 2 blocks/CU), BK=32, double-buffered LDS,
// padded stride 40 f16 to break the 8-way b128 read conflict.

#define AST 40
__global__ __launch_bounds__(256) void gemm_kernel(const _Float16* __restrict__ A,
                                                   const _Float16* __restrict__ Bt,
                                                   float* __restrict__ C)
{
    __shared__ _Float16 As[2][128 * AST];
    __shared__ _Float16 Bs[2][64 * AST];
    const int tid  = threadIdx.x;
    const int by   = blockIdx.x & 31;             // m-tile 0..31
    const int bx   = blockIdx.x >> 5;             // n-tile 0..15
    const int lane = tid & 63;
    const int wid  = tid >> 6;
    const int g = lane >> 4, r = lane & 15;
    const int wm = wid >> 1, wn = wid & 1;

    f32x4 acc[4][2];
    #pragma unroll
    for (int i = 0; i < 4; ++i)
        #pragma unroll
        for (int j = 0; j < 2; ++j) acc[i][j] = (f32x4){0.f,0.f,0.f,0.f};

    const int c0 = tid, c1 = tid + 256;           // A chunks (2/thread), B chunk (1)
    const size_t a0off = (size_t)(by*128 + (c0 >> 2)) * 1024 + (c0 & 3) * 8;
    const size_t a1off = (size_t)(by*128 + (c1 >> 2)) * 1024 + (c1 & 3) * 8;
    const size_t b0off = (size_t)(bx*64  + (c0 >> 2)) * 1024 + (c0 & 3) * 8;
    const int ad0 = (c0 >> 2) * AST + (c0 & 3) * 8;
    const int ad1 = (c1 >> 2) * AST + (c1 & 3) * 8;

    f16x8 a0 = *(const f16x8*)(A  + a0off);
    f16x8 a1 = *(const f16x8*)(A  + a1off);
    f16x8 b0 = *(const f16x8*)(Bt + b0off);
    *(f16x8*)(&As[0][ad0]) = a0;
    *(f16x8*)(&As[0][ad1]) = a1;
    *(f16x8*)(&Bs[0][ad0]) = b0;
    __syncthreads();
    int cur = 0;

    for (int kt = 0; kt < 32; ++kt) {
        if (kt < 31) {
            a0 = *(const f16x8*)(A  + a0off + (kt+1) * 32);
            a1 = *(const f16x8*)(A  + a1off + (kt+1) * 32);
            b0 = *(const f16x8*)(Bt + b0off + (kt+1) * 32);
        }
        f16x8 af[4], bfv[2];
        #pragma unroll
        for (int mi = 0; mi < 4; ++mi)
            af[mi] = *(const f16x8*)(&As[cur][(wm*64 + mi*16 + r) * AST + 8 * g]);
        #pragma unroll
        for (int ni = 0; ni < 2; ++ni)
            bfv[ni] = *(const f16x8*)(&Bs[cur][(wn*32 + ni*16 + r) * AST + 8 * g]);
        __builtin_amdgcn_s_setprio(1);
        #pragma unroll
        for (int mi = 0; mi < 4; ++mi)
            #pragma unroll
            for (int ni = 0; ni < 2; ++ni)
                acc[mi][ni] = __builtin_amdgcn_mfma_f32_16x16x32_f16(
                                  af[mi], bfv[ni], acc[mi][ni], 0, 0, 0);
        __builtin_amdgcn_s_setprio(0);
        if (kt < 31) {
            *(f16x8*)(&As[cur ^ 1][ad0]) = a0;
            *(f16x8*)(&As[cur ^ 1][ad1]) = a1;
            *(f16x8*)(&Bs[cur ^ 1][ad0]) = b0;
            cur ^= 1;
        }
        __syncthreads();
    }
    #pragma unroll
    for (int mi = 0; mi < 4; ++mi)
        #pragma unroll
        for (int ni = 0; ni < 2; ++ni)
            #pragma unroll
            for (int j = 0; j < 4; ++j)
                C[(size_t)(by*128 + wm*64 + mi*16 + 4*g + j) * 1024
                  + bx*64 + wn*32 + ni*16 + r] = acc[mi][ni][j];
}

// ---------------- launch ----------------

extern "C" void kernel_launch(void* const* d_in, const int* in_sizes, int n_in,
                              void* d_out, int out_size, void* d_ws, size_t ws_size,
                              hipStream_t stream) {
    const float* q = (const float*)d_in[0];
    const float* k = (const float*)d_in[1];
    const float* v = (const float*)d_in[2];
    const float* w = (const float*)d_in[3];
    float* out = (float*)d_out;

    char* ws = (char*)d_ws;                       // needs 15 MiB
    float2*   tb = (float2*)(ws);
    _Float16* Kr = (_Float16*)(ws + ((size_t)1 << 20));
    _Float16* Vt = (_Float16*)(ws + ((size_t)3 << 20));
    _Float16* Wt = (_Float16*)(ws + ((size_t)5 << 20));
    _Float16* AO = (_Float16*)(ws + ((size_t)7 << 20));

    hipLaunchKernelGGL(prep_kernel,  dim3(2816), dim3(256), 0, stream, k, v, w, tb, Kr, Vt, Wt);
    hipLaunchKernelGGL(attn_kernel,  dim3(512),  dim3(256), 0, stream, q, tb, Kr, Vt, AO);
    hipLaunchKernelGGL(gemm_kernel,  dim3(512),  dim3(256), 0, stream, AO, Wt, out);
}

// Round 10
// 77.956 us; speedup vs baseline: 1.1924x; 1.1924x over previous
//
#include <hip/hip_runtime.h>
#include <math.h>

#define T_SEQ 2048
#define NH    16
#define NKV   4
// ws layout: tb (sin/cos table, 512KB) @0 ; Kr f16 @1MB (2MB) ; Vt f16 @3MB (2MB) ;
//            Wt f16 @5MB (2MB) ; AO f16 @7MB (8MB). Total 15MB.

typedef __attribute__((ext_vector_type(8)))  _Float16 f16x8;
typedef __attribute__((ext_vector_type(4)))  _Float16 f16x4;
typedef __attribute__((ext_vector_type(4)))  float    f32x4;

// LDS-producer barrier that does NOT drain vmcnt: global prefetch loads stay
// in flight across tiles (T4). lgkmcnt(0) makes this wave's ds_writes
// visible/complete; sched_barrier(0) pins ordering (rule #18).
#define LDS_BARRIER()                                        \
    do {                                                     \
        __builtin_amdgcn_sched_barrier(0);                   \
        asm volatile("s_waitcnt lgkmcnt(0)" ::: "memory");   \
        __builtin_amdgcn_s_barrier();                        \
        __builtin_amdgcn_sched_barrier(0);                   \
    } while (0)

// ---------------- fused prep: table | rope_k(8x amortized) | V-T | W-T ------
__global__ __launch_bounds__(256) void prep_kernel(const float* __restrict__ k,
                                                   const float* __restrict__ v,
                                                   const float* __restrict__ w,
                                                   float2* __restrict__ tb,
                                                   _Float16* __restrict__ Kr,
                                                   _Float16* __restrict__ Vt,
                                                   _Float16* __restrict__ Wt)
{
    __shared__ _Float16 L[64 * 72];
    const int bx = blockIdx.x;
    if (bx < 256) {
        // sin/cos table: tb[t*32+i] = {cos, sin}(t * 10000^(-i/32))
        int idx = bx * 256 + threadIdx.x;
        int i = idx & 31, t = idx >> 5;
        float inv = __expf((float)i * (-9.210340371976184f / 32.0f));
        float ang = (float)t * inv;
        tb[idx] = make_float2(cosf(ang), sinf(ang));
    } else if (bx < 512) {
        // K RoPE: trig once per (t,i), applied to all 8 (b,kh) rows
        int idx = (bx - 256) * 256 + threadIdx.x;     // [0, 2048*32)
        int i   = idx & 31;
        int t   = idx >> 5;
        float inv = __expf((float)i * (-9.210340371976184f / 32.0f));
        float ang = (float)t * inv;
        float sn = sinf(ang), cs = cosf(ang);
        #pragma unroll
        for (int bk = 0; bk < 8; ++bk) {
            const float* src = k + ((size_t)(bk >> 2) * T_SEQ + t) * 256 + (bk & 3) * 64 + i;
            float x1 = src[0], x2 = src[32];
            _Float16* dst = Kr + ((size_t)bk * T_SEQ + t) * 64 + i;
            dst[0]  = (_Float16)(x1 * cs - x2 * sn);
            dst[32] = (_Float16)(x2 * cs + x1 * sn);
        }
    } else if (bx < 768) {
        // V transpose via LDS (both sides coalesced)
        const int id = bx - 512;                      // 32 t-tiles x 8 bk
        const int t0 = (id & 31) * 64, bk = id >> 5;
        const int b = bk >> 2, kh = bk & 3;
        const int rr = threadIdx.x >> 2, pp = threadIdx.x & 3;
        const float* src = v + ((size_t)(b * T_SEQ + t0 + rr)) * 256 + kh * 64 + pp * 16;
        f32x4 s0 = *(const f32x4*)(src), s1 = *(const f32x4*)(src + 4);
        f32x4 s2 = *(const f32x4*)(src + 8), s3 = *(const f32x4*)(src + 12);
        _Float16* lp = &L[rr * 72 + pp * 16];
        #pragma unroll
        for (int j = 0; j < 4; ++j) { lp[j] = (_Float16)s0[j]; lp[4+j] = (_Float16)s1[j];
                                      lp[8+j] = (_Float16)s2[j]; lp[12+j] = (_Float16)s3[j]; }
        __syncthreads();
        f16x8 w0, w1;
        #pragma unroll
        for (int j = 0; j < 8; ++j) w0[j] = L[(pp * 16 + j) * 72 + rr];
        #pragma unroll
        for (int j = 0; j < 8; ++j) w1[j] = L[(pp * 16 + 8 + j) * 72 + rr];
        _Float16* dst = Vt + ((size_t)bk * 64 + rr) * T_SEQ + t0 + pp * 16;
        *(f16x8*)dst = w0; *(f16x8*)(dst + 8) = w1;
    } else {
        // W transpose via LDS
        const int id = bx - 768;                      // 16 k-tiles x 16 n-tiles
        const int k0 = (id & 15) * 64, n0 = (id >> 4) * 64;
        const int rr = threadIdx.x >> 2, pp = threadIdx.x & 3;
        const float* src = w + (size_t)(k0 + rr) * 1024 + n0 + pp * 16;
        f32x4 s0 = *(const f32x4*)(src), s1 = *(const f32x4*)(src + 4);
        f32x4 s2 = *(const f32x4*)(src + 8), s3 = *(const f32x4*)(src + 12);
        _Float16* lp = &L[rr * 72 + pp * 16];
        #pragma unroll
        for (int j = 0; j < 4; ++j) { lp[j] = (_Float16)s0[j]; lp[4+j] = (_Float16)s1[j];
                                      lp[8+j] = (_Float16)s2[j]; lp[12+j] = (_Float16)s3[j]; }
        __syncthreads();
        f16x8 w0, w1;
        #pragma unroll
        for (int j = 0; j < 8; ++j) w0[j] = L[(pp * 16 + j) * 72 + rr];
        #pragma unroll
        for (int j = 0; j < 8; ++j) w1[j] = L[(pp * 16 + 8 + j) * 72 + rr];
        _Float16* dst = Wt + (size_t)(n0 + rr) * 1024 + k0 + pp * 16;
        *(f16x8*)dst = w0; *(f16x8*)(dst + 8) = w1;
    }
}

// ---------------- flash attention (r4 structure + depth-2 + lgkm barrier) ----
// Block = 4 waves handles q-block PAIR (p, 31-p), 64 rows each; EVERY wave
// computes 16 rows of BOTH tiles each KV step (no idle waves). Swapped QK^T;
// inline Q-RoPE; K/V LDS frags shared by both tiles; row-sum via ones-column
// MFMA (o4); lane-local defer-rescale; LDS-bounced epilogue. Depth-2 register
// ping-pong staging + lgkm-only barrier: global prefetch issued a full tile
// before its ds_write -> no per-tile vmcnt stall (T4/T14).

__global__ __launch_bounds__(256) void attn_kernel(const float* __restrict__ q,
                                                   const float2* __restrict__ tb,
                                                   const _Float16* __restrict__ Kr,
                                                   const _Float16* __restrict__ Vt,
                                                   _Float16* __restrict__ AO)
{
    __shared__ _Float16 smem[16384];              // Ks[2]@0/4096, Vs[2]@8192/12288

    const int wid  = threadIdx.x >> 6;
    const int lane = threadIdx.x & 63;
    const int bh = blockIdx.x & 31;               // b*16+h
    const int p  = blockIdx.x >> 5;               // pair id
    const int qb0 = p, qb1 = 31 - p;
    const int b = bh >> 4, h = bh & 15;
    const int kh = h >> 2;
    const int bkh = b * NKV + kh;
    const int g = lane >> 4, r = lane & 15;
    const int NT = qb1 + 1;                       // >= 17

    const int srow   = wid * 16 + (lane >> 3);
    const int schunk = lane & 7;
    const _Float16* kgbase = Kr + (size_t)bkh * T_SEQ * 64;
    const _Float16* vgbase = Vt + (size_t)bkh * 64 * T_SEQ;
    const int kd0 = srow * 64 + ((schunk ^ (srow & 7)) * 8);
    const int kd1 = kd0 + 8 * 64;

    // two named staging register sets (ping-pong; rule #20)
    f16x8 sAK0, sAK1, sAV0, sAV1, sBK0, sBK1, sBV0, sBV1;
    {   // prologue: issue T0 loads first
        const _Float16* kg = kgbase + (size_t)srow * 64 + schunk * 8;
        sAK0 = *(const f16x8*)(kg);
        sAK1 = *(const f16x8*)(kg + 8 * 64);
        const _Float16* vg = vgbase + (size_t)srow * T_SEQ + schunk * 8;
        sAV0 = *(const f16x8*)(vg);
        sAV1 = *(const f16x8*)(vg + 8 * T_SEQ);
    }

    // inline RoPE'd Q fragments for both tiles (pre-scaled by 1/8)
    f16x8 qa[2][2];
    #pragma unroll
    for (int tl = 0; tl < 2; ++tl) {
        const int t = (tl ? qb1 : qb0) * 64 + wid * 16 + r;
        const float* qs = q + ((size_t)b * T_SEQ + t) * 1024 + h * 64 + 8 * g;
        const float2* tp = tb + t * 32 + 8 * g;
        #pragma unroll
        for (int j = 0; j < 8; ++j) {
            float x0 = qs[j], x1 = qs[32 + j];
            float2 cs = tp[j];
            qa[tl][0][j] = (_Float16)((x0 * cs.x - x1 * cs.y) * 0.125f);
            qa[tl][1][j] = (_Float16)((x1 * cs.x + x0 * cs.y) * 0.125f);
        }
    }

    // write T0 -> buf0; issue T1 into setB
    *(f16x8*)(&smem[kd0])        = sAK0;
    *(f16x8*)(&smem[kd1])        = sAK1;
    *(f16x8*)(&smem[8192 + kd0]) = sAV0;
    *(f16x8*)(&smem[8192 + kd1]) = sAV1;
    {
        const _Float16* kg = kgbase + (size_t)(64 + srow) * 64 + schunk * 8;
        sBK0 = *(const f16x8*)(kg);
        sBK1 = *(const f16x8*)(kg + 8 * 64);
        const _Float16* vg = vgbase + (size_t)srow * T_SEQ + 64 + schunk * 8;
        sBV0 = *(const f16x8*)(vg);
        sBV1 = *(const f16x8*)(vg + 8 * T_SEQ);
    }
    LDS_BARRIER();

    f32x4 o[2][4];
    f32x4 o4[2];                                   // row-sum accumulators (ones-col)
    #pragma unroll
    for (int tl = 0; tl < 2; ++tl) {
        #pragma unroll
        for (int db = 0; db < 4; ++db) o[tl][db] = (f32x4){0.f,0.f,0.f,0.f};
        o4[tl] = (f32x4){0.f,0.f,0.f,0.f};
    }
    const f16x4 onesf = {(_Float16)1.f, (_Float16)1.f, (_Float16)1.f, (_Float16)1.f};
    float mrun[2] = {-INFINITY, -INFINITY};

    // tile body: issue T(kvb+2) into set I, compute buf[kvb&1], write set O
    auto tile_body = [&](int kvb,
                         f16x8& iK0, f16x8& iK1, f16x8& iV0, f16x8& iV1,
                         f16x8& oK0, f16x8& oK1, f16x8& oV0, f16x8& oV1) {
        if (kvb + 2 < NT) {
            const int nb = (kvb + 2) * 64;
            const _Float16* kg = kgbase + (size_t)(nb + srow) * 64 + schunk * 8;
            iK0 = *(const f16x8*)(kg);
            iK1 = *(const f16x8*)(kg + 8 * 64);
            const _Float16* vg = vgbase + (size_t)srow * T_SEQ + nb + schunk * 8;
            iV0 = *(const f16x8*)(vg);
            iV1 = *(const f16x8*)(vg + 8 * T_SEQ);
        }
        const bool act0 = (kvb <= qb0);
        const _Float16* ks = smem + (kvb & 1) * 4096;
        const _Float16* vs = smem + 8192 + (kvb & 1) * 4096;

        // ---- QK^T (K frags shared by both q-tiles) ----
        f32x4 stt[2][4];
        __builtin_amdgcn_s_setprio(1);
        #pragma unroll
        for (int kt = 0; kt < 4; ++kt) {
            f16x8 ka0 = *(const f16x8*)(ks + (kt*16 + r) * 64 + ((g       ^ (r & 7)) * 8));
            f16x8 ka1 = *(const f16x8*)(ks + (kt*16 + r) * 64 + (((4 + g) ^ (r & 7)) * 8));
            f32x4 s1 = {0.f,0.f,0.f,0.f};
            s1 = __builtin_amdgcn_mfma_f32_16x16x32_f16(ka0, qa[1][0], s1, 0, 0, 0);
            s1 = __builtin_amdgcn_mfma_f32_16x16x32_f16(ka1, qa[1][1], s1, 0, 0, 0);
            stt[1][kt] = s1;
            if (act0) {
                f32x4 s0 = {0.f,0.f,0.f,0.f};
                s0 = __builtin_amdgcn_mfma_f32_16x16x32_f16(ka0, qa[0][0], s0, 0, 0, 0);
                s0 = __builtin_amdgcn_mfma_f32_16x16x32_f16(ka1, qa[0][1], s0, 0, 0, 0);
                stt[0][kt] = s0;
            }
        }
        __builtin_amdgcn_s_setprio(0);

        // ---- causal masking on diagonal iterations ----
        if (kvb == qb0) {
            #pragma unroll
            for (int kt = 0; kt < 4; ++kt)
                #pragma unroll
                for (int j = 0; j < 4; ++j)
                    if (kt*16 + 4*g + j > wid*16 + r) stt[0][kt][j] = -1e9f;
        }
        if (kvb == qb1) {
            #pragma unroll
            for (int kt = 0; kt < 4; ++kt)
                #pragma unroll
                for (int j = 0; j < 4; ++j)
                    if (kt*16 + 4*g + j > wid*16 + r) stt[1][kt][j] = -1e9f;
        }

        // ---- online softmax (lane-local defer check; sum via o4 MFMA) ----
        f16x4 pf[2][4];
        #pragma unroll
        for (int tl = 0; tl < 2; ++tl) {
            if (tl == 0 && !act0) continue;
            float a0 = fmaxf(fmaxf(stt[tl][0][0], stt[tl][0][1]),
                             fmaxf(stt[tl][0][2], stt[tl][0][3]));
            float a1 = fmaxf(fmaxf(stt[tl][1][0], stt[tl][1][1]),
                             fmaxf(stt[tl][1][2], stt[tl][1][3]));
            float a2 = fmaxf(fmaxf(stt[tl][2][0], stt[tl][2][1]),
                             fmaxf(stt[tl][2][2], stt[tl][2][3]));
            float a3 = fmaxf(fmaxf(stt[tl][3][0], stt[tl][3][1]),
                             fmaxf(stt[tl][3][2], stt[tl][3][3]));
            float pmL = fmaxf(fmaxf(a0, a1), fmaxf(a2, a3));
            if (!__all(pmL <= mrun[tl] + 8.0f)) {   // rare: real max grew
                float pm = fmaxf(pmL, __shfl_xor(pmL, 16));
                pm = fmaxf(pm, __shfl_xor(pm, 32));
                float mn   = fmaxf(mrun[tl], pm);
                float corr = __expf(mrun[tl] - mn);
                mrun[tl]   = mn;
                f32x4 cf = { __shfl(corr, 4*g + 0), __shfl(corr, 4*g + 1),
                             __shfl(corr, 4*g + 2), __shfl(corr, 4*g + 3) };
                o[tl][0] *= cf; o[tl][1] *= cf; o[tl][2] *= cf; o[tl][3] *= cf;
                o4[tl]   *= cf;
            }
            #pragma unroll
            for (int kt = 0; kt < 4; ++kt) {
                float p0 = __expf(stt[tl][kt][0] - mrun[tl]);
                float p1 = __expf(stt[tl][kt][1] - mrun[tl]);
                float p2 = __expf(stt[tl][kt][2] - mrun[tl]);
                float p3 = __expf(stt[tl][kt][3] - mrun[tl]);
                pf[tl][kt] = (f16x4){(_Float16)p0, (_Float16)p1,
                                     (_Float16)p2, (_Float16)p3};
            }
        }

        // ---- PV + row-sum (V frags shared by both q-tiles) ----
        __builtin_amdgcn_s_setprio(1);
        #pragma unroll
        for (int kt = 0; kt < 4; ++kt) {
            const int vc = ((2*kt + (g >> 1)) ^ (r & 7)) * 8 + (g & 1) * 4;
            f16x4 v0 = *(const f16x4*)(vs + (0*16 + r) * 64 + vc);
            f16x4 v1 = *(const f16x4*)(vs + (1*16 + r) * 64 + vc);
            f16x4 v2 = *(const f16x4*)(vs + (2*16 + r) * 64 + vc);
            f16x4 v3 = *(const f16x4*)(vs + (3*16 + r) * 64 + vc);
            o[1][0] = __builtin_amdgcn_mfma_f32_16x16x16f16(pf[1][kt], v0, o[1][0], 0, 0, 0);
            o[1][1] = __builtin_amdgcn_mfma_f32_16x16x16f16(pf[1][kt], v1, o[1][1], 0, 0, 0);
            o[1][2] = __builtin_amdgcn_mfma_f32_16x16x16f16(pf[1][kt], v2, o[1][2], 0, 0, 0);
            o[1][3] = __builtin_amdgcn_mfma_f32_16x16x16f16(pf[1][kt], v3, o[1][3], 0, 0, 0);
            o4[1]   = __builtin_amdgcn_mfma_f32_16x16x16f16(pf[1][kt], onesf, o4[1], 0, 0, 0);
            if (act0) {
                o[0][0] = __builtin_amdgcn_mfma_f32_16x16x16f16(pf[0][kt], v0, o[0][0], 0, 0, 0);
                o[0][1] = __builtin_amdgcn_mfma_f32_16x16x16f16(pf[0][kt], v1, o[0][1], 0, 0, 0);
                o[0][2] = __builtin_amdgcn_mfma_f32_16x16x16f16(pf[0][kt], v2, o[0][2], 0, 0, 0);
                o[0][3] = __builtin_amdgcn_mfma_f32_16x16x16f16(pf[0][kt], v3, o[0][3], 0, 0, 0);
                o4[0]   = __builtin_amdgcn_mfma_f32_16x16x16f16(pf[0][kt], onesf, o4[0], 0, 0, 0);
            }
        }
        __builtin_amdgcn_s_setprio(0);

        // write T(kvb+1): its loads were issued a full tile ago (no vm stall)
        if (kvb + 1 < NT) {
            _Float16* kw = smem + ((kvb + 1) & 1) * 4096;
            _Float16* vw = smem + 8192 + ((kvb + 1) & 1) * 4096;
            *(f16x8*)(&kw[kd0]) = oK0;
            *(f16x8*)(&kw[kd1]) = oK1;
            *(f16x8*)(&vw[kd0]) = oV0;
            *(f16x8*)(&vw[kd1]) = oV1;
        }
        LDS_BARRIER();   // drains LDS only; global prefetch stays in flight
    };

    for (int t = 0; t < NT; ) {
        tile_body(t, sAK0, sAK1, sAV0, sAV1, sBK0, sBK1, sBV0, sBV1); ++t;
        if (t >= NT) break;
        tile_body(t, sBK0, sBK1, sBV0, sBV1, sAK0, sAK1, sAV0, sAV1); ++t;
    }

    // ---- epilogue: lane-local normalize, LDS bounce, coalesced AO stores ----
    #pragma unroll
    for (int tl = 0; tl < 2; ++tl) {
        f32x4 li;
        #pragma unroll
        for (int j = 0; j < 4; ++j) li[j] = 1.0f / o4[tl][j];
        _Float16* Os = smem + tl * 4608;          // [64][72] f16
        #pragma unroll
        for (int db = 0; db < 4; ++db) {
            f32x4 ov = o[tl][db] * li;
            #pragma unroll
            for (int j = 0; j < 4; ++j)
                Os[(wid*16 + 4*g + j) * 72 + db*16 + r] = (_Float16)ov[j];
        }
    }
    __syncthreads();
    {
        const int row = threadIdx.x >> 2, part = threadIdx.x & 3;
        #pragma unroll
        for (int tl = 0; tl < 2; ++tl) {
            const int qb = tl ? qb1 : qb0;
            const _Float16* src = smem + tl * 4608 + row * 72 + part * 16;
            _Float16* dst = AO + ((size_t)b * T_SEQ + qb * 64 + row) * 1024 + h * 64 + part * 16;
            *(f16x8*)dst       = *(const f16x8*)src;
            *(f16x8*)(dst + 8) = *(const f16x8*)(src + 8);
        }
    }
}

// ---------------- projection GEMM: out[4096][1024] = AO * Wt^T ----------------
// 128x64 tile (512 blocks -> 2 blocks/CU), BK=32, double-buffered LDS,
// padded stride 40 f16 to break the 8-way b128 read conflict.

#define AST 40
__global__ __launch_bounds__(256) void gemm_kernel(const _Float16* __restrict__ A,
                                                   const _Float16* __restrict__ Bt,
                                                   float* __restrict__ C)
{
    __shared__ _Float16 As[2][128 * AST];
    __shared__ _Float16 Bs[2][64 * AST];
    const int tid  = threadIdx.x;
    const int by   = blockIdx.x & 31;             // m-tile 0..31
    const int bx   = blockIdx.x >> 5;             // n-tile 0..15
    const int lane = tid & 63;
    const int wid  = tid >> 6;
    const int g = lane >> 4, r = lane & 15;
    const int wm = wid >> 1, wn = wid & 1;

    f32x4 acc[4][2];
    #pragma unroll
    for (int i = 0; i < 4; ++i)
        #pragma unroll
        for (int j = 0; j < 2; ++j) acc[i][j] = (f32x4){0.f,0.f,0.f,0.f};

    const int c0 = tid, c1 = tid + 256;           // A chunks (2/thread), B chunk (1)
    const size_t a0off = (size_t)(by*128 + (c0 >> 2)) * 1024 + (c0 & 3) * 8;
    const size_t a1off = (size_t)(by*128 + (c1 >> 2)) * 1024 + (c1 & 3) * 8;
    const size_t b0off = (size_t)(bx*64  + (c0 >> 2)) * 1024 + (c0 & 3) * 8;
    const int ad0 = (c0 >> 2) * AST + (c0 & 3) * 8;
    const int ad1 = (c1 >> 2) * AST + (c1 & 3) * 8;

    f16x8 a0 = *(const f16x8*)(A  + a0off);
    f16x8 a1 = *(const f16x8*)(A  + a1off);
    f16x8 b0 = *(const f16x8*)(Bt + b0off);
    *(f16x8*)(&As[0][ad0]) = a0;
    *(f16x8*)(&As[0][ad1]) = a1;
    *(f16x8*)(&Bs[0][ad0]) = b0;
    __syncthreads();
    int cur = 0;

    for (int kt = 0; kt < 32; ++kt) {
        if (kt < 31) {
            a0 = *(const f16x8*)(A  + a0off + (kt+1) * 32);
            a1 = *(const f16x8*)(A  + a1off + (kt+1) * 32);
            b0 = *(const f16x8*)(Bt + b0off + (kt+1) * 32);
        }
        f16x8 af[4], bfv[2];
        #pragma unroll
        for (int mi = 0; mi < 4; ++mi)
            af[mi] = *(const f16x8*)(&As[cur][(wm*64 + mi*16 + r) * AST + 8 * g]);
        #pragma unroll
        for (int ni = 0; ni < 2; ++ni)
            bfv[ni] = *(const f16x8*)(&Bs[cur][(wn*32 + ni*16 + r) * AST + 8 * g]);
        __builtin_amdgcn_s_setprio(1);
        #pragma unroll
        for (int mi = 0; mi < 4; ++mi)
            #pragma unroll
            for (int ni = 0; ni < 2; ++ni)
                acc[mi][ni] = __builtin_amdgcn_mfma_f32_16x16x32_f16(
                                  af[mi], bfv[ni], acc[mi][ni], 0, 0, 0);
        __builtin_amdgcn_s_setprio(0);
        if (kt < 31) {
            *(f16x8*)(&As[cur ^ 1][ad0]) = a0;
            *(f16x8*)(&As[cur ^ 1][ad1]) = a1;
            *(f16x8*)(&Bs[cur ^ 1][ad0]) = b0;
            cur ^= 1;
        }
        __syncthreads();
    }
    #pragma unroll
    for (int mi = 0; mi < 4; ++mi)
        #pragma unroll
        for (int ni = 0; ni < 2; ++ni)
            #pragma unroll
            for (int j = 0; j < 4; ++j)
                C[(size_t)(by*128 + wm*64 + mi*16 + 4*g + j) * 1024
                  + bx*64 + wn*32 + ni*16 + r] = acc[mi][ni][j];
}

// ---------------- launch ----------------

extern "C" void kernel_launch(void* const* d_in, const int* in_sizes, int n_in,
                              void* d_out, int out_size, void* d_ws, size_t ws_size,
                              hipStream_t stream) {
    const float* q = (const float*)d_in[0];
    const float* k = (const float*)d_in[1];
    const float* v = (const float*)d_in[2];
    const float* w = (const float*)d_in[3];
    float* out = (float*)d_out;

    char* ws = (char*)d_ws;                       // needs 15 MiB
    float2*   tb = (float2*)(ws);
    _Float16* Kr = (_Float16*)(ws + ((size_t)1 << 20));
    _Float16* Vt = (_Float16*)(ws + ((size_t)3 << 20));
    _Float16* Wt = (_Float16*)(ws + ((size_t)5 << 20));
    _Float16* AO = (_Float16*)(ws + ((size_t)7 << 20));

    hipLaunchKernelGGL(prep_kernel,  dim3(1024), dim3(256), 0, stream, k, v, w, tb, Kr, Vt, Wt);
    hipLaunchKernelGGL(attn_kernel,  dim3(512),  dim3(256), 0, stream, q, tb, Kr, Vt, AO);
    hipLaunchKernelGGL(gemm_kernel,  dim3(512),  dim3(256), 0, stream, AO, Wt, out);
}

// Round 11
// 74.462 us; speedup vs baseline: 1.2484x; 1.0469x over previous
//
#include <hip/hip_runtime.h>
#include <math.h>

#define T_SEQ 2048
#define NH    16
#define NKV   4
// ws layout: tb (sin/cos table, 512KB) @0 ; Kr f16 @1MB (2MB) ; Vt f16 @3MB (2MB) ;
//            Wt f16 @5MB (2MB) ; AO f16 @7MB (8MB). Total 15MB.

typedef __attribute__((ext_vector_type(8)))  _Float16 f16x8;
typedef __attribute__((ext_vector_type(4)))  _Float16 f16x4;
typedef __attribute__((ext_vector_type(2)))  __fp16   fp16x2b;  // cvt_pkrtz result type
typedef __attribute__((ext_vector_type(4)))  float    f32x4;

#if __has_builtin(__builtin_amdgcn_exp2f)
#define EXP2F(x) __builtin_amdgcn_exp2f(x)
#else
#define EXP2F(x) exp2f(x)
#endif

// 0.125 (1/sqrt(64)) * log2(e): QK^T scores land directly in log2 domain.
#define QSCALE 0.18033688011112042f

// ---------------- fused prep: table | rope_k(8x amortized) | V-T | W-T ------
__global__ __launch_bounds__(256) void prep_kernel(const float* __restrict__ k,
                                                   const float* __restrict__ v,
                                                   const float* __restrict__ w,
                                                   float2* __restrict__ tb,
                                                   _Float16* __restrict__ Kr,
                                                   _Float16* __restrict__ Vt,
                                                   _Float16* __restrict__ Wt)
{
    __shared__ _Float16 L[64 * 72];
    const int bx = blockIdx.x;
    if (bx < 256) {
        // sin/cos table: tb[t*32+i] = {cos, sin}(t * 10000^(-i/32))
        int idx = bx * 256 + threadIdx.x;
        int i = idx & 31, t = idx >> 5;
        float inv = __expf((float)i * (-9.210340371976184f / 32.0f));
        float ang = (float)t * inv;
        tb[idx] = make_float2(cosf(ang), sinf(ang));
    } else if (bx < 512) {
        // K RoPE: trig once per (t,i), applied to all 8 (b,kh) rows
        int idx = (bx - 256) * 256 + threadIdx.x;     // [0, 2048*32)
        int i   = idx & 31;
        int t   = idx >> 5;
        float inv = __expf((float)i * (-9.210340371976184f / 32.0f));
        float ang = (float)t * inv;
        float sn = sinf(ang), cs = cosf(ang);
        #pragma unroll
        for (int bk = 0; bk < 8; ++bk) {
            const float* src = k + ((size_t)(bk >> 2) * T_SEQ + t) * 256 + (bk & 3) * 64 + i;
            float x1 = src[0], x2 = src[32];
            _Float16* dst = Kr + ((size_t)bk * T_SEQ + t) * 64 + i;
            dst[0]  = (_Float16)(x1 * cs - x2 * sn);
            dst[32] = (_Float16)(x2 * cs + x1 * sn);
        }
    } else if (bx < 768) {
        // V transpose via LDS (both sides coalesced)
        const int id = bx - 512;                      // 32 t-tiles x 8 bk
        const int t0 = (id & 31) * 64, bk = id >> 5;
        const int b = bk >> 2, kh = bk & 3;
        const int rr = threadIdx.x >> 2, pp = threadIdx.x & 3;
        const float* src = v + ((size_t)(b * T_SEQ + t0 + rr)) * 256 + kh * 64 + pp * 16;
        f32x4 s0 = *(const f32x4*)(src), s1 = *(const f32x4*)(src + 4);
        f32x4 s2 = *(const f32x4*)(src + 8), s3 = *(const f32x4*)(src + 12);
        _Float16* lp = &L[rr * 72 + pp * 16];
        #pragma unroll
        for (int j = 0; j < 4; ++j) { lp[j] = (_Float16)s0[j]; lp[4+j] = (_Float16)s1[j];
                                      lp[8+j] = (_Float16)s2[j]; lp[12+j] = (_Float16)s3[j]; }
        __syncthreads();
        f16x8 w0, w1;
        #pragma unroll
        for (int j = 0; j < 8; ++j) w0[j] = L[(pp * 16 + j) * 72 + rr];
        #pragma unroll
        for (int j = 0; j < 8; ++j) w1[j] = L[(pp * 16 + 8 + j) * 72 + rr];
        _Float16* dst = Vt + ((size_t)bk * 64 + rr) * T_SEQ + t0 + pp * 16;
        *(f16x8*)dst = w0; *(f16x8*)(dst + 8) = w1;
    } else {
        // W transpose via LDS
        const int id = bx - 768;                      // 16 k-tiles x 16 n-tiles
        const int k0 = (id & 15) * 64, n0 = (id >> 4) * 64;
        const int rr = threadIdx.x >> 2, pp = threadIdx.x & 3;
        const float* src = w + (size_t)(k0 + rr) * 1024 + n0 + pp * 16;
        f32x4 s0 = *(const f32x4*)(src), s1 = *(const f32x4*)(src + 4);
        f32x4 s2 = *(const f32x4*)(src + 8), s3 = *(const f32x4*)(src + 12);
        _Float16* lp = &L[rr * 72 + pp * 16];
        #pragma unroll
        for (int j = 0; j < 4; ++j) { lp[j] = (_Float16)s0[j]; lp[4+j] = (_Float16)s1[j];
                                      lp[8+j] = (_Float16)s2[j]; lp[12+j] = (_Float16)s3[j]; }
        __syncthreads();
        f16x8 w0, w1;
        #pragma unroll
        for (int j = 0; j < 8; ++j) w0[j] = L[(pp * 16 + j) * 72 + rr];
        #pragma unroll
        for (int j = 0; j < 8; ++j) w1[j] = L[(pp * 16 + 8 + j) * 72 + rr];
        _Float16* dst = Wt + (size_t)(n0 + rr) * 1024 + k0 + pp * 16;
        *(f16x8*)dst = w0; *(f16x8*)(dst + 8) = w1;
    }
}

// ---------------- flash attention (r4 structure, CU-balanced p remap) -------
// Block = 4 waves handles q-block PAIR (p, 31-p); every wave computes 16 rows
// of BOTH tiles each KV step. p remapped so CU-coresident blocks (bid i,
// i+256) get complementary p and 15-p: per-CU total = 49 tiles on EVERY CU.
// Swapped QK^T; inline Q-RoPE (log2-domain scale); K/V LDS frags shared by
// both tiles; row-sum via ones-column MFMA; lane-local defer-rescale (exp2);
// cvt_pkrtz P-packing; LDS-bounced epilogue.

__global__ __launch_bounds__(256) void attn_kernel(const float* __restrict__ q,
                                                   const float2* __restrict__ tb,
                                                   const _Float16* __restrict__ Kr,
                                                   const _Float16* __restrict__ Vt,
                                                   _Float16* __restrict__ AO)
{
    __shared__ _Float16 smem[16384];              // Ks[2]|Vs[2]; reused as Os[2]

    const int wid  = threadIdx.x >> 6;
    const int lane = threadIdx.x & 63;
    const int bh = blockIdx.x & 31;               // b*16+h
    const int pp = blockIdx.x >> 5;
    const int p  = (pp < 8) ? pp : (23 - pp);     // CU pairs: totals 49 everywhere
    const int qb0 = p, qb1 = 31 - p;
    const int b = bh >> 4, h = bh & 15;
    const int kh = h >> 2;
    const int bkh = b * NKV + kh;
    const int g = lane >> 4, r = lane & 15;

    const int srow   = wid * 16 + (lane >> 3);
    const int schunk = lane & 7;
    const _Float16* kgbase = Kr + (size_t)bkh * T_SEQ * 64;
    const _Float16* vgbase = Vt + (size_t)bkh * 64 * T_SEQ;
    const int kd0 = srow * 64 + ((schunk ^ (srow & 7)) * 8);
    const int kd1 = kd0 + 8 * 64;

    f16x8 stK0, stK1, stV0, stV1;
    {   // prologue: issue tile-0 global loads first
        const _Float16* kg = kgbase + (size_t)srow * 64 + schunk * 8;
        stK0 = *(const f16x8*)(kg);
        stK1 = *(const f16x8*)(kg + 8 * 64);
        const _Float16* vg = vgbase + (size_t)srow * T_SEQ + schunk * 8;
        stV0 = *(const f16x8*)(vg);
        stV1 = *(const f16x8*)(vg + 8 * T_SEQ);
    }

    // inline RoPE'd Q fragments for both tiles (scaled by 0.125*log2e)
    f16x8 qa[2][2];
    #pragma unroll
    for (int tl = 0; tl < 2; ++tl) {
        const int t = (tl ? qb1 : qb0) * 64 + wid * 16 + r;
        const float* qs = q + ((size_t)b * T_SEQ + t) * 1024 + h * 64 + 8 * g;
        const float2* tp = tb + t * 32 + 8 * g;
        #pragma unroll
        for (int j = 0; j < 8; ++j) {
            float x0 = qs[j], x1 = qs[32 + j];
            float2 cs = tp[j];
            qa[tl][0][j] = (_Float16)((x0 * cs.x - x1 * cs.y) * QSCALE);
            qa[tl][1][j] = (_Float16)((x1 * cs.x + x0 * cs.y) * QSCALE);
        }
    }

    *(f16x8*)(&smem[kd0])        = stK0;          // Ks[0]
    *(f16x8*)(&smem[kd1])        = stK1;
    *(f16x8*)(&smem[8192 + kd0]) = stV0;          // Vs[0]
    *(f16x8*)(&smem[8192 + kd1]) = stV1;
    __syncthreads();

    f32x4 o[2][4];
    f32x4 o4[2];                                   // row-sum accumulators (ones-col)
    #pragma unroll
    for (int tl = 0; tl < 2; ++tl) {
        #pragma unroll
        for (int db = 0; db < 4; ++db) o[tl][db] = (f32x4){0.f,0.f,0.f,0.f};
        o4[tl] = (f32x4){0.f,0.f,0.f,0.f};
    }
    const f16x4 onesf = {(_Float16)1.f, (_Float16)1.f, (_Float16)1.f, (_Float16)1.f};
    float mrun[2] = {-INFINITY, -INFINITY};
    int cur = 0;

    for (int kvb = 0; kvb <= qb1; ++kvb) {
        const bool hasNext = (kvb < qb1);
        if (hasNext) {
            const int nb = (kvb + 1) * 64;
            const _Float16* kg = kgbase + (size_t)(nb + srow) * 64 + schunk * 8;
            stK0 = *(const f16x8*)(kg);
            stK1 = *(const f16x8*)(kg + 8 * 64);
            const _Float16* vg = vgbase + (size_t)srow * T_SEQ + nb + schunk * 8;
            stV0 = *(const f16x8*)(vg);
            stV1 = *(const f16x8*)(vg + 8 * T_SEQ);
        }
        const bool act0 = (kvb <= qb0);
        const _Float16* ks = smem + cur * 4096;
        const _Float16* vs = smem + 8192 + cur * 4096;

        // ---- QK^T (K frags shared by both q-tiles) ----
        f32x4 stt[2][4];
        __builtin_amdgcn_s_setprio(1);
        #pragma unroll
        for (int kt = 0; kt < 4; ++kt) {
            f16x8 ka0 = *(const f16x8*)(ks + (kt*16 + r) * 64 + ((g       ^ (r & 7)) * 8));
            f16x8 ka1 = *(const f16x8*)(ks + (kt*16 + r) * 64 + (((4 + g) ^ (r & 7)) * 8));
            f32x4 s1 = {0.f,0.f,0.f,0.f};
            s1 = __builtin_amdgcn_mfma_f32_16x16x32_f16(ka0, qa[1][0], s1, 0, 0, 0);
            s1 = __builtin_amdgcn_mfma_f32_16x16x32_f16(ka1, qa[1][1], s1, 0, 0, 0);
            stt[1][kt] = s1;
            if (act0) {
                f32x4 s0 = {0.f,0.f,0.f,0.f};
                s0 = __builtin_amdgcn_mfma_f32_16x16x32_f16(ka0, qa[0][0], s0, 0, 0, 0);
                s0 = __builtin_amdgcn_mfma_f32_16x16x32_f16(ka1, qa[0][1], s0, 0, 0, 0);
                stt[0][kt] = s0;
            }
        }
        __builtin_amdgcn_s_setprio(0);

        // ---- causal masking on diagonal iterations ----
        if (kvb == qb0) {
            #pragma unroll
            for (int kt = 0; kt < 4; ++kt)
                #pragma unroll
                for (int j = 0; j < 4; ++j)
                    if (kt*16 + 4*g + j > wid*16 + r) stt[0][kt][j] = -1e9f;
        }
        if (kvb == qb1) {
            #pragma unroll
            for (int kt = 0; kt < 4; ++kt)
                #pragma unroll
                for (int j = 0; j < 4; ++j)
                    if (kt*16 + 4*g + j > wid*16 + r) stt[1][kt][j] = -1e9f;
        }

        // ---- online softmax (log2 domain; lane-local defer; sum via o4) ----
        f16x4 pf[2][4];
        #pragma unroll
        for (int tl = 0; tl < 2; ++tl) {
            if (tl == 0 && !act0) continue;
            float a0 = fmaxf(fmaxf(stt[tl][0][0], stt[tl][0][1]),
                             fmaxf(stt[tl][0][2], stt[tl][0][3]));
            float a1 = fmaxf(fmaxf(stt[tl][1][0], stt[tl][1][1]),
                             fmaxf(stt[tl][1][2], stt[tl][1][3]));
            float a2 = fmaxf(fmaxf(stt[tl][2][0], stt[tl][2][1]),
                             fmaxf(stt[tl][2][2], stt[tl][2][3]));
            float a3 = fmaxf(fmaxf(stt[tl][3][0], stt[tl][3][1]),
                             fmaxf(stt[tl][3][2], stt[tl][3][3]));
            float pmL = fmaxf(fmaxf(a0, a1), fmaxf(a2, a3));
            if (!__all(pmL <= mrun[tl] + 8.0f)) {   // rare: real max grew
                float pm = fmaxf(pmL, __shfl_xor(pmL, 16));
                pm = fmaxf(pm, __shfl_xor(pm, 32));
                float mn   = fmaxf(mrun[tl], pm);
                float corr = EXP2F(mrun[tl] - mn);
                mrun[tl]   = mn;
                f32x4 cf = { __shfl(corr, 4*g + 0), __shfl(corr, 4*g + 1),
                             __shfl(corr, 4*g + 2), __shfl(corr, 4*g + 3) };
                o[tl][0] *= cf; o[tl][1] *= cf; o[tl][2] *= cf; o[tl][3] *= cf;
                o4[tl]   *= cf;
            }
            #pragma unroll
            for (int kt = 0; kt < 4; ++kt) {
                float p0 = EXP2F(stt[tl][kt][0] - mrun[tl]);
                float p1 = EXP2F(stt[tl][kt][1] - mrun[tl]);
                float p2 = EXP2F(stt[tl][kt][2] - mrun[tl]);
                float p3 = EXP2F(stt[tl][kt][3] - mrun[tl]);
                union { unsigned u[2]; f16x4 v; } pk;
                union { fp16x2b hh; unsigned u; } c0, c1;
                c0.hh = __builtin_amdgcn_cvt_pkrtz(p0, p1);
                c1.hh = __builtin_amdgcn_cvt_pkrtz(p2, p3);
                pk.u[0] = c0.u; pk.u[1] = c1.u;
                pf[tl][kt] = pk.v;
            }
        }

        // ---- PV + row-sum (V frags shared by both q-tiles) ----
        __builtin_amdgcn_s_setprio(1);
        #pragma unroll
        for (int kt = 0; kt < 4; ++kt) {
            const int vc = ((2*kt + (g >> 1)) ^ (r & 7)) * 8 + (g & 1) * 4;
            f16x4 v0 = *(const f16x4*)(vs + (0*16 + r) * 64 + vc);
            f16x4 v1 = *(const f16x4*)(vs + (1*16 + r) * 64 + vc);
            f16x4 v2 = *(const f16x4*)(vs + (2*16 + r) * 64 + vc);
            f16x4 v3 = *(const f16x4*)(vs + (3*16 + r) * 64 + vc);
            o[1][0] = __builtin_amdgcn_mfma_f32_16x16x16f16(pf[1][kt], v0, o[1][0], 0, 0, 0);
            o[1][1] = __builtin_amdgcn_mfma_f32_16x16x16f16(pf[1][kt], v1, o[1][1], 0, 0, 0);
            o[1][2] = __builtin_amdgcn_mfma_f32_16x16x16f16(pf[1][kt], v2, o[1][2], 0, 0, 0);
            o[1][3] = __builtin_amdgcn_mfma_f32_16x16x16f16(pf[1][kt], v3, o[1][3], 0, 0, 0);
            o4[1]   = __builtin_amdgcn_mfma_f32_16x16x16f16(pf[1][kt], onesf, o4[1], 0, 0, 0);
            if (act0) {
                o[0][0] = __builtin_amdgcn_mfma_f32_16x16x16f16(pf[0][kt], v0, o[0][0], 0, 0, 0);
                o[0][1] = __builtin_amdgcn_mfma_f32_16x16x16f16(pf[0][kt], v1, o[0][1], 0, 0, 0);
                o[0][2] = __builtin_amdgcn_mfma_f32_16x16x16f16(pf[0][kt], v2, o[0][2], 0, 0, 0);
                o[0][3] = __builtin_amdgcn_mfma_f32_16x16x16f16(pf[0][kt], v3, o[0][3], 0, 0, 0);
                o4[0]   = __builtin_amdgcn_mfma_f32_16x16x16f16(pf[0][kt], onesf, o4[0], 0, 0, 0);
            }
        }
        __builtin_amdgcn_s_setprio(0);

        if (hasNext) {
            _Float16* kw = smem + (cur ^ 1) * 4096;
            _Float16* vw = smem + 8192 + (cur ^ 1) * 4096;
            *(f16x8*)(&kw[kd0]) = stK0;
            *(f16x8*)(&kw[kd1]) = stK1;
            *(f16x8*)(&vw[kd0]) = stV0;
            *(f16x8*)(&vw[kd1]) = stV1;
            cur ^= 1;
        }
        __syncthreads();
    }

    // ---- epilogue: lane-local normalize, LDS bounce, coalesced AO stores ----
    #pragma unroll
    for (int tl = 0; tl < 2; ++tl) {
        f32x4 li;
        #pragma unroll
        for (int j = 0; j < 4; ++j) li[j] = 1.0f / o4[tl][j];
        _Float16* Os = smem + tl * 4608;          // [64][72] f16
        #pragma unroll
        for (int db = 0; db < 4; ++db) {
            f32x4 ov = o[tl][db] * li;
            #pragma unroll
            for (int j = 0; j < 4; ++j)
                Os[(wid*16 + 4*g + j) * 72 + db*16 + r] = (_Float16)ov[j];
        }
    }
    __syncthreads();
    {
        const int row = threadIdx.x >> 2, part = threadIdx.x & 3;
        #pragma unroll
        for (int tl = 0; tl < 2; ++tl) {
            const int qb = tl ? qb1 : qb0;
            const _Float16* src = smem + tl * 4608 + row * 72 + part * 16;
            _Float16* dst = AO + ((size_t)b * T_SEQ + qb * 64 + row) * 1024 + h * 64 + part * 16;
            *(f16x8*)dst       = *(const f16x8*)src;
            *(f16x8*)(dst + 8) = *(const f16x8*)(src + 8);
        }
    }
}

// ---------------- projection GEMM: out[4096][1024] = AO * Wt^T ----------------
// 128x64 tile (512 blocks -> 2 blocks/CU), BK=32, double-buffered LDS,
// padded stride 40 f16 to break the 8-way b128 read conflict.

#define AST 40
__global__ __launch_bounds__(256) void gemm_kernel(const _Float16* __restrict__ A,
                                                   const _Float16* __restrict__ Bt,
                                                   float* __restrict__ C)
{
    __shared__ _Float16 As[2][128 * AST];
    __shared__ _Float16 Bs[2][64 * AST];
    const int tid  = threadIdx.x;
    const int by   = blockIdx.x & 31;             // m-tile 0..31
    const int bx   = blockIdx.x >> 5;             // n-tile 0..15
    const int lane = tid & 63;
    const int wid  = tid >> 6;
    const int g = lane >> 4, r = lane & 15;
    const int wm = wid >> 1, wn = wid & 1;

    f32x4 acc[4][2];
    #pragma unroll
    for (int i = 0; i < 4; ++i)
        #pragma unroll
        for (int j = 0; j < 2; ++j) acc[i][j] = (f32x4){0.f,0.f,0.f,0.f};

    const int c0 = tid, c1 = tid + 256;           // A chunks (2/thread), B chunk (1)
    const size_t a0off = (size_t)(by*128 + (c0 >> 2)) * 1024 + (c0 & 3) * 8;
    const size_t a1off = (size_t)(by*128 + (c1 >> 2)) * 1024 + (c1 & 3) * 8;
    const size_t b0off = (size_t)(bx*64  + (c0 >> 2)) * 1024 + (c0 & 3) * 8;
    const int ad0 = (c0 >> 2) * AST + (c0 & 3) * 8;
    const int ad1 = (c1 >> 2) * AST + (c1 & 3) * 8;

    f16x8 a0 = *(const f16x8*)(A  + a0off);
    f16x8 a1 = *(const f16x8*)(A  + a1off);
    f16x8 b0 = *(const f16x8*)(Bt + b0off);
    *(f16x8*)(&As[0][ad0]) = a0;
    *(f16x8*)(&As[0][ad1]) = a1;
    *(f16x8*)(&Bs[0][ad0]) = b0;
    __syncthreads();
    int cur = 0;

    for (int kt = 0; kt < 32; ++kt) {
        if (kt < 31) {
            a0 = *(const f16x8*)(A  + a0off + (kt+1) * 32);
            a1 = *(const f16x8*)(A  + a1off + (kt+1) * 32);
            b0 = *(const f16x8*)(Bt + b0off + (kt+1) * 32);
        }
        f16x8 af[4], bfv[2];
        #pragma unroll
        for (int mi = 0; mi < 4; ++mi)
            af[mi] = *(const f16x8*)(&As[cur][(wm*64 + mi*16 + r) * AST + 8 * g]);
        #pragma unroll
        for (int ni = 0; ni < 2; ++ni)
            bfv[ni] = *(const f16x8*)(&Bs[cur][(wn*32 + ni*16 + r) * AST + 8 * g]);
        __builtin_amdgcn_s_setprio(1);
        #pragma unroll
        for (int mi = 0; mi < 4; ++mi)
            #pragma unroll
            for (int ni = 0; ni < 2; ++ni)
                acc[mi][ni] = __builtin_amdgcn_mfma_f32_16x16x32_f16(
                                  af[mi], bfv[ni], acc[mi][ni], 0, 0, 0);
        __builtin_amdgcn_s_setprio(0);
        if (kt < 31) {
            *(f16x8*)(&As[cur ^ 1][ad0]) = a0;
            *(f16x8*)(&As[cur ^ 1][ad1]) = a1;
            *(f16x8*)(&Bs[cur ^ 1][ad0]) = b0;
            cur ^= 1;
        }
        __syncthreads();
    }
    #pragma unroll
    for (int mi = 0; mi < 4; ++mi)
        #pragma unroll
        for (int ni = 0; ni < 2; ++ni)
            #pragma unroll
            for (int j = 0; j < 4; ++j)
                C[(size_t)(by*128 + wm*64 + mi*16 + 4*g + j) * 1024
                  + bx*64 + wn*32 + ni*16 + r] = acc[mi][ni][j];
}

// ---------------- launch ----------------

extern "C" void kernel_launch(void* const* d_in, const int* in_sizes, int n_in,
                              void* d_out, int out_size, void* d_ws, size_t ws_size,
                              hipStream_t stream) {
    const float* q = (const float*)d_in[0];
    const float* k = (const float*)d_in[1];
    const float* v = (const float*)d_in[2];
    const float* w = (const float*)d_in[3];
    float* out = (float*)d_out;

    char* ws = (char*)d_ws;                       // needs 15 MiB
    float2*   tb = (float2*)(ws);
    _Float16* Kr = (_Float16*)(ws + ((size_t)1 << 20));
    _Float16* Vt = (_Float16*)(ws + ((size_t)3 << 20));
    _Float16* Wt = (_Float16*)(ws + ((size_t)5 << 20));
    _Float16* AO = (_Float16*)(ws + ((size_t)7 << 20));

    hipLaunchKernelGGL(prep_kernel,  dim3(1024), dim3(256), 0, stream, k, v, w, tb, Kr, Vt, Wt);
    hipLaunchKernelGGL(attn_kernel,  dim3(512),  dim3(256), 0, stream, q, tb, Kr, Vt, AO);
    hipLaunchKernelGGL(gemm_kernel,  dim3(512),  dim3(256), 0, stream, AO, Wt, out);
}

// Round 12
// 72.588 us; speedup vs baseline: 1.2806x; 1.0258x over previous
//
#include <hip/hip_runtime.h>
#include <math.h>

#define T_SEQ 2048
#define NH    16
#define NKV   4
// ws layout: tb (sin/cos table, 512KB) @0 ; Kr f16 @1MB (2MB) ; Vt f16 @3MB (2MB) ;
//            Wt f16 @5MB (2MB) ; AO f16 @7MB (8MB). Total 15MB.

typedef __attribute__((ext_vector_type(8)))  _Float16 f16x8;
typedef __attribute__((ext_vector_type(4)))  _Float16 f16x4;
typedef __attribute__((ext_vector_type(2)))  __fp16   fp16x2b;  // cvt_pkrtz result type
typedef __attribute__((ext_vector_type(4)))  float    f32x4;

#if __has_builtin(__builtin_amdgcn_exp2f)
#define EXP2F(x) __builtin_amdgcn_exp2f(x)
#else
#define EXP2F(x) exp2f(x)
#endif

// 0.125 (1/sqrt(64)) * log2(e): QK^T scores land directly in log2 domain.
#define QSCALE 0.18033688011112042f

// LDS-producer barrier that does NOT drain vmcnt: global prefetch loads stay
// in flight across iterations (T4). lgkmcnt(0) makes this wave's ds_writes
// visible/complete; sched_barrier(0) pins ordering (rule #18).
#define LDS_BARRIER()                                        \
    do {                                                     \
        __builtin_amdgcn_sched_barrier(0);                   \
        asm volatile("s_waitcnt lgkmcnt(0)" ::: "memory");   \
        __builtin_amdgcn_s_barrier();                        \
        __builtin_amdgcn_sched_barrier(0);                   \
    } while (0)

// ---------------- fused prep: table | rope_k(8x amortized) | V-T | W-T ------
__global__ __launch_bounds__(256) void prep_kernel(const float* __restrict__ k,
                                                   const float* __restrict__ v,
                                                   const float* __restrict__ w,
                                                   float2* __restrict__ tb,
                                                   _Float16* __restrict__ Kr,
                                                   _Float16* __restrict__ Vt,
                                                   _Float16* __restrict__ Wt)
{
    __shared__ _Float16 L[64 * 72];
    const int bx = blockIdx.x;
    if (bx < 256) {
        // sin/cos table: tb[t*32+i] = {cos, sin}(t * 10000^(-i/32))
        int idx = bx * 256 + threadIdx.x;
        int i = idx & 31, t = idx >> 5;
        float inv = __expf((float)i * (-9.210340371976184f / 32.0f));
        float ang = (float)t * inv;
        tb[idx] = make_float2(cosf(ang), sinf(ang));
    } else if (bx < 512) {
        // K RoPE: trig once per (t,i), applied to all 8 (b,kh) rows
        int idx = (bx - 256) * 256 + threadIdx.x;     // [0, 2048*32)
        int i   = idx & 31;
        int t   = idx >> 5;
        float inv = __expf((float)i * (-9.210340371976184f / 32.0f));
        float ang = (float)t * inv;
        float sn = sinf(ang), cs = cosf(ang);
        #pragma unroll
        for (int bk = 0; bk < 8; ++bk) {
            const float* src = k + ((size_t)(bk >> 2) * T_SEQ + t) * 256 + (bk & 3) * 64 + i;
            float x1 = src[0], x2 = src[32];
            _Float16* dst = Kr + ((size_t)bk * T_SEQ + t) * 64 + i;
            dst[0]  = (_Float16)(x1 * cs - x2 * sn);
            dst[32] = (_Float16)(x2 * cs + x1 * sn);
        }
    } else if (bx < 768) {
        // V transpose via LDS (both sides coalesced)
        const int id = bx - 512;                      // 32 t-tiles x 8 bk
        const int t0 = (id & 31) * 64, bk = id >> 5;
        const int b = bk >> 2, kh = bk & 3;
        const int rr = threadIdx.x >> 2, pp = threadIdx.x & 3;
        const float* src = v + ((size_t)(b * T_SEQ + t0 + rr)) * 256 + kh * 64 + pp * 16;
        f32x4 s0 = *(const f32x4*)(src), s1 = *(const f32x4*)(src + 4);
        f32x4 s2 = *(const f32x4*)(src + 8), s3 = *(const f32x4*)(src + 12);
        _Float16* lp = &L[rr * 72 + pp * 16];
        #pragma unroll
        for (int j = 0; j < 4; ++j) { lp[j] = (_Float16)s0[j]; lp[4+j] = (_Float16)s1[j];
                                      lp[8+j] = (_Float16)s2[j]; lp[12+j] = (_Float16)s3[j]; }
        __syncthreads();
        f16x8 w0, w1;
        #pragma unroll
        for (int j = 0; j < 8; ++j) w0[j] = L[(pp * 16 + j) * 72 + rr];
        #pragma unroll
        for (int j = 0; j < 8; ++j) w1[j] = L[(pp * 16 + 8 + j) * 72 + rr];
        _Float16* dst = Vt + ((size_t)bk * 64 + rr) * T_SEQ + t0 + pp * 16;
        *(f16x8*)dst = w0; *(f16x8*)(dst + 8) = w1;
    } else {
        // W transpose via LDS
        const int id = bx - 768;                      // 16 k-tiles x 16 n-tiles
        const int k0 = (id & 15) * 64, n0 = (id >> 4) * 64;
        const int rr = threadIdx.x >> 2, pp = threadIdx.x & 3;
        const float* src = w + (size_t)(k0 + rr) * 1024 + n0 + pp * 16;
        f32x4 s0 = *(const f32x4*)(src), s1 = *(const f32x4*)(src + 4);
        f32x4 s2 = *(const f32x4*)(src + 8), s3 = *(const f32x4*)(src + 12);
        _Float16* lp = &L[rr * 72 + pp * 16];
        #pragma unroll
        for (int j = 0; j < 4; ++j) { lp[j] = (_Float16)s0[j]; lp[4+j] = (_Float16)s1[j];
                                      lp[8+j] = (_Float16)s2[j]; lp[12+j] = (_Float16)s3[j]; }
        __syncthreads();
        f16x8 w0, w1;
        #pragma unroll
        for (int j = 0; j < 8; ++j) w0[j] = L[(pp * 16 + j) * 72 + rr];
        #pragma unroll
        for (int j = 0; j < 8; ++j) w1[j] = L[(pp * 16 + 8 + j) * 72 + rr];
        _Float16* dst = Wt + (size_t)(n0 + rr) * 1024 + k0 + pp * 16;
        *(f16x8*)dst = w0; *(f16x8*)(dst + 8) = w1;
    }
}

// ---------------- flash attention (r11, unchanged) --------------------------
// Block = 4 waves handles q-block PAIR (p, 31-p); every wave computes 16 rows
// of BOTH tiles each KV step. p remapped so CU-coresident blocks (bid i,
// i+256) get complementary p and 15-p: per-CU total = 49 tiles on EVERY CU.
// Swapped QK^T; inline Q-RoPE (log2-domain scale); K/V LDS frags shared by
// both tiles; row-sum via ones-column MFMA; lane-local defer-rescale (exp2);
// cvt_pkrtz P-packing; LDS-bounced epilogue.

__global__ __launch_bounds__(256) void attn_kernel(const float* __restrict__ q,
                                                   const float2* __restrict__ tb,
                                                   const _Float16* __restrict__ Kr,
                                                   const _Float16* __restrict__ Vt,
                                                   _Float16* __restrict__ AO)
{
    __shared__ _Float16 smem[16384];              // Ks[2]|Vs[2]; reused as Os[2]

    const int wid  = threadIdx.x >> 6;
    const int lane = threadIdx.x & 63;
    const int bh = blockIdx.x & 31;               // b*16+h
    const int pp = blockIdx.x >> 5;
    const int p  = (pp < 8) ? pp : (23 - pp);     // CU pairs: totals 49 everywhere
    const int qb0 = p, qb1 = 31 - p;
    const int b = bh >> 4, h = bh & 15;
    const int kh = h >> 2;
    const int bkh = b * NKV + kh;
    const int g = lane >> 4, r = lane & 15;

    const int srow   = wid * 16 + (lane >> 3);
    const int schunk = lane & 7;
    const _Float16* kgbase = Kr + (size_t)bkh * T_SEQ * 64;
    const _Float16* vgbase = Vt + (size_t)bkh * 64 * T_SEQ;
    const int kd0 = srow * 64 + ((schunk ^ (srow & 7)) * 8);
    const int kd1 = kd0 + 8 * 64;

    f16x8 stK0, stK1, stV0, stV1;
    {   // prologue: issue tile-0 global loads first
        const _Float16* kg = kgbase + (size_t)srow * 64 + schunk * 8;
        stK0 = *(const f16x8*)(kg);
        stK1 = *(const f16x8*)(kg + 8 * 64);
        const _Float16* vg = vgbase + (size_t)srow * T_SEQ + schunk * 8;
        stV0 = *(const f16x8*)(vg);
        stV1 = *(const f16x8*)(vg + 8 * T_SEQ);
    }

    // inline RoPE'd Q fragments for both tiles (scaled by 0.125*log2e)
    f16x8 qa[2][2];
    #pragma unroll
    for (int tl = 0; tl < 2; ++tl) {
        const int t = (tl ? qb1 : qb0) * 64 + wid * 16 + r;
        const float* qs = q + ((size_t)b * T_SEQ + t) * 1024 + h * 64 + 8 * g;
        const float2* tp = tb + t * 32 + 8 * g;
        #pragma unroll
        for (int j = 0; j < 8; ++j) {
            float x0 = qs[j], x1 = qs[32 + j];
            float2 cs = tp[j];
            qa[tl][0][j] = (_Float16)((x0 * cs.x - x1 * cs.y) * QSCALE);
            qa[tl][1][j] = (_Float16)((x1 * cs.x + x0 * cs.y) * QSCALE);
        }
    }

    *(f16x8*)(&smem[kd0])        = stK0;          // Ks[0]
    *(f16x8*)(&smem[kd1])        = stK1;
    *(f16x8*)(&smem[8192 + kd0]) = stV0;          // Vs[0]
    *(f16x8*)(&smem[8192 + kd1]) = stV1;
    __syncthreads();

    f32x4 o[2][4];
    f32x4 o4[2];                                   // row-sum accumulators (ones-col)
    #pragma unroll
    for (int tl = 0; tl < 2; ++tl) {
        #pragma unroll
        for (int db = 0; db < 4; ++db) o[tl][db] = (f32x4){0.f,0.f,0.f,0.f};
        o4[tl] = (f32x4){0.f,0.f,0.f,0.f};
    }
    const f16x4 onesf = {(_Float16)1.f, (_Float16)1.f, (_Float16)1.f, (_Float16)1.f};
    float mrun[2] = {-INFINITY, -INFINITY};
    int cur = 0;

    for (int kvb = 0; kvb <= qb1; ++kvb) {
        const bool hasNext = (kvb < qb1);
        if (hasNext) {
            const int nb = (kvb + 1) * 64;
            const _Float16* kg = kgbase + (size_t)(nb + srow) * 64 + schunk * 8;
            stK0 = *(const f16x8*)(kg);
            stK1 = *(const f16x8*)(kg + 8 * 64);
            const _Float16* vg = vgbase + (size_t)srow * T_SEQ + nb + schunk * 8;
            stV0 = *(const f16x8*)(vg);
            stV1 = *(const f16x8*)(vg + 8 * T_SEQ);
        }
        const bool act0 = (kvb <= qb0);
        const _Float16* ks = smem + cur * 4096;
        const _Float16* vs = smem + 8192 + cur * 4096;

        // ---- QK^T (K frags shared by both q-tiles) ----
        f32x4 stt[2][4];
        __builtin_amdgcn_s_setprio(1);
        #pragma unroll
        for (int kt = 0; kt < 4; ++kt) {
            f16x8 ka0 = *(const f16x8*)(ks + (kt*16 + r) * 64 + ((g       ^ (r & 7)) * 8));
            f16x8 ka1 = *(const f16x8*)(ks + (kt*16 + r) * 64 + (((4 + g) ^ (r & 7)) * 8));
            f32x4 s1 = {0.f,0.f,0.f,0.f};
            s1 = __builtin_amdgcn_mfma_f32_16x16x32_f16(ka0, qa[1][0], s1, 0, 0, 0);
            s1 = __builtin_amdgcn_mfma_f32_16x16x32_f16(ka1, qa[1][1], s1, 0, 0, 0);
            stt[1][kt] = s1;
            if (act0) {
                f32x4 s0 = {0.f,0.f,0.f,0.f};
                s0 = __builtin_amdgcn_mfma_f32_16x16x32_f16(ka0, qa[0][0], s0, 0, 0, 0);
                s0 = __builtin_amdgcn_mfma_f32_16x16x32_f16(ka1, qa[0][1], s0, 0, 0, 0);
                stt[0][kt] = s0;
            }
        }
        __builtin_amdgcn_s_setprio(0);

        // ---- causal masking on diagonal iterations ----
        if (kvb == qb0) {
            #pragma unroll
            for (int kt = 0; kt < 4; ++kt)
                #pragma unroll
                for (int j = 0; j < 4; ++j)
                    if (kt*16 + 4*g + j > wid*16 + r) stt[0][kt][j] = -1e9f;
        }
        if (kvb == qb1) {
            #pragma unroll
            for (int kt = 0; kt < 4; ++kt)
                #pragma unroll
                for (int j = 0; j < 4; ++j)
                    if (kt*16 + 4*g + j > wid*16 + r) stt[1][kt][j] = -1e9f;
        }

        // ---- online softmax (log2 domain; lane-local defer; sum via o4) ----
        f16x4 pf[2][4];
        #pragma unroll
        for (int tl = 0; tl < 2; ++tl) {
            if (tl == 0 && !act0) continue;
            float a0 = fmaxf(fmaxf(stt[tl][0][0], stt[tl][0][1]),
                             fmaxf(stt[tl][0][2], stt[tl][0][3]));
            float a1 = fmaxf(fmaxf(stt[tl][1][0], stt[tl][1][1]),
                             fmaxf(stt[tl][1][2], stt[tl][1][3]));
            float a2 = fmaxf(fmaxf(stt[tl][2][0], stt[tl][2][1]),
                             fmaxf(stt[tl][2][2], stt[tl][2][3]));
            float a3 = fmaxf(fmaxf(stt[tl][3][0], stt[tl][3][1]),
                             fmaxf(stt[tl][3][2], stt[tl][3][3]));
            float pmL = fmaxf(fmaxf(a0, a1), fmaxf(a2, a3));
            if (!__all(pmL <= mrun[tl] + 8.0f)) {   // rare: real max grew
                float pm = fmaxf(pmL, __shfl_xor(pmL, 16));
                pm = fmaxf(pm, __shfl_xor(pm, 32));
                float mn   = fmaxf(mrun[tl], pm);
                float corr = EXP2F(mrun[tl] - mn);
                mrun[tl]   = mn;
                f32x4 cf = { __shfl(corr, 4*g + 0), __shfl(corr, 4*g + 1),
                             __shfl(corr, 4*g + 2), __shfl(corr, 4*g + 3) };
                o[tl][0] *= cf; o[tl][1] *= cf; o[tl][2] *= cf; o[tl][3] *= cf;
                o4[tl]   *= cf;
            }
            #pragma unroll
            for (int kt = 0; kt < 4; ++kt) {
                float p0 = EXP2F(stt[tl][kt][0] - mrun[tl]);
                float p1 = EXP2F(stt[tl][kt][1] - mrun[tl]);
                float p2 = EXP2F(stt[tl][kt][2] - mrun[tl]);
                float p3 = EXP2F(stt[tl][kt][3] - mrun[tl]);
                union { unsigned u[2]; f16x4 v; } pk;
                union { fp16x2b hh; unsigned u; } c0, c1;
                c0.hh = __builtin_amdgcn_cvt_pkrtz(p0, p1);
                c1.hh = __builtin_amdgcn_cvt_pkrtz(p2, p3);
                pk.u[0] = c0.u; pk.u[1] = c1.u;
                pf[tl][kt] = pk.v;
            }
        }

        // ---- PV + row-sum (V frags shared by both q-tiles) ----
        __builtin_amdgcn_s_setprio(1);
        #pragma unroll
        for (int kt = 0; kt < 4; ++kt) {
            const int vc = ((2*kt + (g >> 1)) ^ (r & 7)) * 8 + (g & 1) * 4;
            f16x4 v0 = *(const f16x4*)(vs + (0*16 + r) * 64 + vc);
            f16x4 v1 = *(const f16x4*)(vs + (1*16 + r) * 64 + vc);
            f16x4 v2 = *(const f16x4*)(vs + (2*16 + r) * 64 + vc);
            f16x4 v3 = *(const f16x4*)(vs + (3*16 + r) * 64 + vc);
            o[1][0] = __builtin_amdgcn_mfma_f32_16x16x16f16(pf[1][kt], v0, o[1][0], 0, 0, 0);
            o[1][1] = __builtin_amdgcn_mfma_f32_16x16x16f16(pf[1][kt], v1, o[1][1], 0, 0, 0);
            o[1][2] = __builtin_amdgcn_mfma_f32_16x16x16f16(pf[1][kt], v2, o[1][2], 0, 0, 0);
            o[1][3] = __builtin_amdgcn_mfma_f32_16x16x16f16(pf[1][kt], v3, o[1][3], 0, 0, 0);
            o4[1]   = __builtin_amdgcn_mfma_f32_16x16x16f16(pf[1][kt], onesf, o4[1], 0, 0, 0);
            if (act0) {
                o[0][0] = __builtin_amdgcn_mfma_f32_16x16x16f16(pf[0][kt], v0, o[0][0], 0, 0, 0);
                o[0][1] = __builtin_amdgcn_mfma_f32_16x16x16f16(pf[0][kt], v1, o[0][1], 0, 0, 0);
                o[0][2] = __builtin_amdgcn_mfma_f32_16x16x16f16(pf[0][kt], v2, o[0][2], 0, 0, 0);
                o[0][3] = __builtin_amdgcn_mfma_f32_16x16x16f16(pf[0][kt], v3, o[0][3], 0, 0, 0);
                o4[0]   = __builtin_amdgcn_mfma_f32_16x16x16f16(pf[0][kt], onesf, o4[0], 0, 0, 0);
            }
        }
        __builtin_amdgcn_s_setprio(0);

        if (hasNext) {
            _Float16* kw = smem + (cur ^ 1) * 4096;
            _Float16* vw = smem + 8192 + (cur ^ 1) * 4096;
            *(f16x8*)(&kw[kd0]) = stK0;
            *(f16x8*)(&kw[kd1]) = stK1;
            *(f16x8*)(&vw[kd0]) = stV0;
            *(f16x8*)(&vw[kd1]) = stV1;
            cur ^= 1;
        }
        __syncthreads();
    }

    // ---- epilogue: lane-local normalize, LDS bounce, coalesced AO stores ----
    #pragma unroll
    for (int tl = 0; tl < 2; ++tl) {
        f32x4 li;
        #pragma unroll
        for (int j = 0; j < 4; ++j) li[j] = 1.0f / o4[tl][j];
        _Float16* Os = smem + tl * 4608;          // [64][72] f16
        #pragma unroll
        for (int db = 0; db < 4; ++db) {
            f32x4 ov = o[tl][db] * li;
            #pragma unroll
            for (int j = 0; j < 4; ++j)
                Os[(wid*16 + 4*g + j) * 72 + db*16 + r] = (_Float16)ov[j];
        }
    }
    __syncthreads();
    {
        const int row = threadIdx.x >> 2, part = threadIdx.x & 3;
        #pragma unroll
        for (int tl = 0; tl < 2; ++tl) {
            const int qb = tl ? qb1 : qb0;
            const _Float16* src = smem + tl * 4608 + row * 72 + part * 16;
            _Float16* dst = AO + ((size_t)b * T_SEQ + qb * 64 + row) * 1024 + h * 64 + part * 16;
            *(f16x8*)dst       = *(const f16x8*)src;
            *(f16x8*)(dst + 8) = *(const f16x8*)(src + 8);
        }
    }
}

// ---------------- projection GEMM: out[4096][1024] = AO * Wt^T ----------------
// 128x64 tile (512 blocks -> 2 blocks/CU), BK=32, depth-2 register ping-pong:
// at iter kt issue loads for kt+2, ds_write the (long-complete) kt+1 set,
// lgkm-only barrier -> global loads stay in flight across barriers (no
// per-iter vmcnt(0) drain). Padded stride 40 f16 breaks b128 read conflicts.

#define AST 40
__global__ __launch_bounds__(256) void gemm_kernel(const _Float16* __restrict__ A,
                                                   const _Float16* __restrict__ Bt,
                                                   float* __restrict__ C)
{
    __shared__ _Float16 As[2][128 * AST];
    __shared__ _Float16 Bs[2][64 * AST];
    const int tid  = threadIdx.x;
    const int by   = blockIdx.x & 31;             // m-tile 0..31
    const int bx   = blockIdx.x >> 5;             // n-tile 0..15
    const int lane = tid & 63;
    const int wid  = tid >> 6;
    const int g = lane >> 4, r = lane & 15;
    const int wm = wid >> 1, wn = wid & 1;

    f32x4 acc[4][2];
    #pragma unroll
    for (int i = 0; i < 4; ++i)
        #pragma unroll
        for (int j = 0; j < 2; ++j) acc[i][j] = (f32x4){0.f,0.f,0.f,0.f};

    const int c0 = tid, c1 = tid + 256;           // A chunks (2/thread), B chunk (1)
    const size_t a0off = (size_t)(by*128 + (c0 >> 2)) * 1024 + (c0 & 3) * 8;
    const size_t a1off = (size_t)(by*128 + (c1 >> 2)) * 1024 + (c1 & 3) * 8;
    const size_t b0off = (size_t)(bx*64  + (c0 >> 2)) * 1024 + (c0 & 3) * 8;
    const int ad0 = (c0 >> 2) * AST + (c0 & 3) * 8;
    const int ad1 = (c1 >> 2) * AST + (c1 & 3) * 8;

    // prologue: T0 -> LDS[0]; T1 into set B (in flight)
    f16x8 pA0 = *(const f16x8*)(A  + a0off);
    f16x8 pA1 = *(const f16x8*)(A  + a1off);
    f16x8 pB0 = *(const f16x8*)(Bt + b0off);
    *(f16x8*)(&As[0][ad0]) = pA0;
    *(f16x8*)(&As[0][ad1]) = pA1;
    *(f16x8*)(&Bs[0][ad0]) = pB0;
    f16x8 sA0B = *(const f16x8*)(A  + a0off + 32);
    f16x8 sA1B = *(const f16x8*)(A  + a1off + 32);
    f16x8 sB0B = *(const f16x8*)(Bt + b0off + 32);
    f16x8 sA0A, sA1A, sB0A;
    __syncthreads();

    // iter body: issue loads for kt+2 into set I, compute LDS[kt&1],
    // write set O (tile kt+1, issued a full iter ago) to LDS[(kt+1)&1].
    auto iter_body = [&](int kt,
                         f16x8& iA0, f16x8& iA1, f16x8& iB0,
                         f16x8& oA0, f16x8& oA1, f16x8& oB0) {
        if (kt + 2 < 32) {
            iA0 = *(const f16x8*)(A  + a0off + (kt + 2) * 32);
            iA1 = *(const f16x8*)(A  + a1off + (kt + 2) * 32);
            iB0 = *(const f16x8*)(Bt + b0off + (kt + 2) * 32);
        }
        const int cur = kt & 1;
        f16x8 af[4], bfv[2];
        #pragma unroll
        for (int mi = 0; mi < 4; ++mi)
            af[mi] = *(const f16x8*)(&As[cur][(wm*64 + mi*16 + r) * AST + 8 * g]);
        #pragma unroll
        for (int ni = 0; ni < 2; ++ni)
            bfv[ni] = *(const f16x8*)(&Bs[cur][(wn*32 + ni*16 + r) * AST + 8 * g]);
        __builtin_amdgcn_s_setprio(1);
        #pragma unroll
        for (int mi = 0; mi < 4; ++mi)
            #pragma unroll
            for (int ni = 0; ni < 2; ++ni)
                acc[mi][ni] = __builtin_amdgcn_mfma_f32_16x16x32_f16(
                                  af[mi], bfv[ni], acc[mi][ni], 0, 0, 0);
        __builtin_amdgcn_s_setprio(0);
        if (kt + 1 < 32) {
            *(f16x8*)(&As[cur ^ 1][ad0]) = oA0;
            *(f16x8*)(&As[cur ^ 1][ad1]) = oA1;
            *(f16x8*)(&Bs[cur ^ 1][ad0]) = oB0;
        }
        LDS_BARRIER();   // drains LDS only; global prefetch stays in flight
    };

    #pragma unroll 2
    for (int kt = 0; kt < 32; kt += 2) {
        iter_body(kt,     sA0A, sA1A, sB0A, sA0B, sA1B, sB0B);
        iter_body(kt + 1, sA0B, sA1B, sB0B, sA0A, sA1A, sB0A);
    }

    #pragma unroll
    for (int mi = 0; mi < 4; ++mi)
        #pragma unroll
        for (int ni = 0; ni < 2; ++ni)
            #pragma unroll
            for (int j = 0; j < 4; ++j)
                C[(size_t)(by*128 + wm*64 + mi*16 + 4*g + j) * 1024
                  + bx*64 + wn*32 + ni*16 + r] = acc[mi][ni][j];
}

// ---------------- launch ----------------

extern "C" void kernel_launch(void* const* d_in, const int* in_sizes, int n_in,
                              void* d_out, int out_size, void* d_ws, size_t ws_size,
                              hipStream_t stream) {
    const float* q = (const float*)d_in[0];
    const float* k = (const float*)d_in[1];
    const float* v = (const float*)d_in[2];
    const float* w = (const float*)d_in[3];
    float* out = (float*)d_out;

    char* ws = (char*)d_ws;                       // needs 15 MiB
    float2*   tb = (float2*)(ws);
    _Float16* Kr = (_Float16*)(ws + ((size_t)1 << 20));
    _Float16* Vt = (_Float16*)(ws + ((size_t)3 << 20));
    _Float16* Wt = (_Float16*)(ws + ((size_t)5 << 20));
    _Float16* AO = (_Float16*)(ws + ((size_t)7 << 20));

    hipLaunchKernelGGL(prep_kernel,  dim3(1024), dim3(256), 0, stream, k, v, w, tb, Kr, Vt, Wt);
    hipLaunchKernelGGL(attn_kernel,  dim3(512),  dim3(256), 0, stream, q, tb, Kr, Vt, AO);
    hipLaunchKernelGGL(gemm_kernel,  dim3(512),  dim3(256), 0, stream, AO, Wt, out);
}